// Round 2
// baseline (1054.461 us; speedup 1.0000x reference)
//
#include <hip/hip_runtime.h>
#include <hip/hip_bf16.h>

#define F_IN 8
#define HID 64

typedef __hip_bfloat16 bf16;

__device__ __forceinline__ float b2f(bf16 x) { return __bfloat162float(x); }
__device__ __forceinline__ bf16 f2b(float x) { return __float2bfloat16(x); }

template <typename T> struct IO;
template <> struct IO<bf16> {
    static __device__ __forceinline__ float ld(const bf16* p, size_t i) { return b2f(p[i]); }
    static __device__ __forceinline__ void st(bf16* p, size_t i, float v) { p[i] = f2b(v); }
};
template <> struct IO<float> {
    static __device__ __forceinline__ float ld(const float* p, size_t i) { return p[i]; }
    static __device__ __forceinline__ void st(float* p, size_t i, float v) { p[i] = v; }
};

// K0: dtype vote. bf16 data: low 16 bits of each word are a bf16 ~N(0,1) ->
// exponent in narrow band (~100%). f32 data: low bits are mantissa noise (~16%).
__global__ void dec_detect_kernel(const unsigned int* __restrict__ xraw, int* __restrict__ flag) {
    int t = threadIdx.x;
    int cnt = 0;
    for (int j = 0; j < 4; ++j) {
        unsigned w = xraw[t * 4 + j];
        unsigned lo = w & 0xFFFFu;
        unsigned e = (lo >> 7) & 0xFFu;
        if (lo == 0u || (e >= 100u && e <= 144u)) cnt++;
    }
#pragma unroll
    for (int off = 32; off > 0; off >>= 1) cnt += __shfl_xor(cnt, off);
    if (t == 0) *flag = (cnt >= 128) ? 1 : 0;
}

template <typename T>
__device__ __forceinline__ void deg_body(const int* __restrict__ ei, const T* __restrict__ ew,
                                         float* __restrict__ deg_w, int* __restrict__ count, int E) {
    int e = blockIdx.x * blockDim.x + threadIdx.x;
    if (e >= E) return;
    int dst = ei[E + e];
    atomicAdd(&deg_w[dst], IO<T>::ld(ew, e));
    atomicAdd(&count[dst], 1);
}
__global__ void dec_deg_kernel(const int* ei, const void* ew, float* deg_w, int* count, int E,
                               const int* flag) {
    if (*flag) deg_body<bf16>(ei, (const bf16*)ew, deg_w, count, E);
    else       deg_body<float>(ei, (const float*)ew, deg_w, count, E);
}

__global__ __launch_bounds__(1024) void dec_scan_kernel(const int* __restrict__ count,
                                                        float* __restrict__ dinv,
                                                        int* __restrict__ rowstart, int n) {
    __shared__ int sdata[1024];
    __shared__ int s_carry;
    if (threadIdx.x == 0) s_carry = 0;
    __syncthreads();
    for (int base = 0; base < n; base += 1024) {
        int i = base + (int)threadIdx.x;
        int v = (i < n) ? count[i] : 0;
        if (i < n) dinv[i] = rsqrtf(dinv[i] + 1.0f);
        sdata[threadIdx.x] = v;
        __syncthreads();
        int incl = v;
        for (int off = 1; off < 1024; off <<= 1) {
            int other = (threadIdx.x >= off) ? sdata[threadIdx.x - off] : 0;
            __syncthreads();
            incl += other;
            sdata[threadIdx.x] = incl;
            __syncthreads();
        }
        if (i < n) rowstart[i] = s_carry + incl - v;
        int total = sdata[1023];
        __syncthreads();
        if (threadIdx.x == 0) s_carry += total;
        __syncthreads();
    }
    if (threadIdx.x == 0) rowstart[n] = s_carry;
}

template <typename T>
__device__ __forceinline__ void scatter_body(const int* __restrict__ ei, const T* __restrict__ ew,
                                             const float* __restrict__ dinv,
                                             const int* __restrict__ rowstart,
                                             int* __restrict__ cursor, int* __restrict__ csr_src,
                                             float* __restrict__ csr_norm, int E) {
    int e = blockIdx.x * blockDim.x + threadIdx.x;
    if (e >= E) return;
    int src = ei[e];
    int dst = ei[E + e];
    int pos = rowstart[dst] + atomicAdd(&cursor[dst], 1);
    csr_src[pos] = src;
    csr_norm[pos] = dinv[dst] * IO<T>::ld(ew, e) * dinv[src];
}
__global__ void dec_scatter_kernel(const int* ei, const void* ew, const float* dinv,
                                   const int* rowstart, int* cursor, int* csr_src,
                                   float* csr_norm, int E, const int* flag) {
    if (*flag) scatter_body<bf16>(ei, (const bf16*)ew, dinv, rowstart, cursor, csr_src, csr_norm, E);
    else       scatter_body<float>(ei, (const float*)ew, dinv, rowstart, cursor, csr_src, csr_norm, E);
}

template <typename T>
__device__ __forceinline__ void aggA_body(const int* __restrict__ rowstart,
                                          const int* __restrict__ csr_src,
                                          const float* __restrict__ csr_norm,
                                          const float* __restrict__ dinv,
                                          const T* __restrict__ X, const T* __restrict__ H,
                                          bf16* __restrict__ axah, int n) {
    int wave = threadIdx.x >> 6;
    int lane = threadIdx.x & 63;
    int i = blockIdx.x * 4 + wave;
    if (i >= n) return;
    float di = dinv[i];
    float self = di * di;
    float acc_h = self * IO<T>::ld(H, (size_t)i * 64 + lane);
    float acc_x = (lane < F_IN) ? self * IO<T>::ld(X, (size_t)i * F_IN + lane) : 0.f;
    int s0 = rowstart[i], s1 = rowstart[i + 1];
    for (int e = s0; e < s1; ++e) {
        int s = csr_src[e];
        float nrm = csr_norm[e];
        acc_h += nrm * IO<T>::ld(H, (size_t)s * 64 + lane);
        if (lane < F_IN) acc_x += nrm * IO<T>::ld(X, (size_t)s * F_IN + lane);
    }
    axah[(size_t)i * 72 + lane] = f2b(acc_h);
    if (lane < F_IN) axah[(size_t)i * 72 + 64 + lane] = f2b(acc_x);
}
__global__ __launch_bounds__(256) void dec_aggA_kernel(const int* rowstart, const int* csr_src,
                                                       const float* csr_norm, const float* dinv,
                                                       const void* X, const void* H,
                                                       bf16* axah, int n, const int* flag) {
    if (*flag) aggA_body<bf16>(rowstart, csr_src, csr_norm, dinv, (const bf16*)X, (const bf16*)H, axah, n);
    else       aggA_body<float>(rowstart, csr_src, csr_norm, dinv, (const float*)X, (const float*)H, axah, n);
}

template <typename T>
__device__ __forceinline__ void gates_body(
    const bf16* __restrict__ axah, const T* __restrict__ Cin,
    const T* __restrict__ Wx, const T* __restrict__ bx,
    const T* __restrict__ Wh, const T* __restrict__ bh,
    const T* __restrict__ wc, const T* __restrict__ bg,
    const T* __restrict__ lnh_s, const T* __restrict__ lnh_b,
    const T* __restrict__ lnc_s, const T* __restrict__ lnc_b,
    const T* __restrict__ lno_s, const T* __restrict__ lno_b,
    const T* __restrict__ skip, const T* __restrict__ W1,
    bf16* __restrict__ t_out, T* __restrict__ dout, int n) {
    const int k = threadIdx.x;
    const int base = blockIdx.x * 8;
    T* out_hidden = dout + n;                       // element offsets within d_out
    T* out_cell   = dout + n + (size_t)64 * n;
    __shared__ float sh_axah[8 * 72];
    __shared__ float sh_u[8 * 66];
    int cnt = n - base; if (cnt > 8) cnt = 8; if (cnt < 0) cnt = 0;
    for (int idx = k; idx < cnt * 72; idx += 64)
        sh_axah[idx] = b2f(axah[(size_t)base * 72 + idx]);
    __syncthreads();

    float acc0[8] = {}, acc1[8] = {}, acc2[8] = {}, acc3[8] = {};
    for (int h = 0; h < HID; ++h) {
        float w0 = IO<T>::ld(Wh, 0 * 4096 + h * 64 + k);
        float w1 = IO<T>::ld(Wh, 1 * 4096 + h * 64 + k);
        float w2 = IO<T>::ld(Wh, 2 * 4096 + h * 64 + k);
        float w3 = IO<T>::ld(Wh, 3 * 4096 + h * 64 + k);
#pragma unroll
        for (int nn = 0; nn < 8; ++nn) {
            float a = sh_axah[nn * 72 + h];
            acc0[nn] = fmaf(a, w0, acc0[nn]);
            acc1[nn] = fmaf(a, w1, acc1[nn]);
            acc2[nn] = fmaf(a, w2, acc2[nn]);
            acc3[nn] = fmaf(a, w3, acc3[nn]);
        }
    }
    for (int f = 0; f < F_IN; ++f) {
        float w0 = IO<T>::ld(Wx, 0 * 512 + f * 64 + k);
        float w1 = IO<T>::ld(Wx, 1 * 512 + f * 64 + k);
        float w2 = IO<T>::ld(Wx, 2 * 512 + f * 64 + k);
        float w3 = IO<T>::ld(Wx, 3 * 512 + f * 64 + k);
#pragma unroll
        for (int nn = 0; nn < 8; ++nn) {
            float a = sh_axah[nn * 72 + 64 + f];
            acc0[nn] = fmaf(a, w0, acc0[nn]);
            acc1[nn] = fmaf(a, w1, acc1[nn]);
            acc2[nn] = fmaf(a, w2, acc2[nn]);
            acc3[nn] = fmaf(a, w3, acc3[nn]);
        }
    }

    float B0 = IO<T>::ld(bx, k)       + IO<T>::ld(bh, k)       + IO<T>::ld(bg, k);
    float B1 = IO<T>::ld(bx, 64 + k)  + IO<T>::ld(bh, 64 + k)  + IO<T>::ld(bg, 64 + k);
    float B2 = IO<T>::ld(bx, 128 + k) + IO<T>::ld(bh, 128 + k) + IO<T>::ld(bg, 128 + k);
    float B3 = IO<T>::ld(bx, 192 + k) + IO<T>::ld(bh, 192 + k) + IO<T>::ld(bg, 192 + k);
    float pc0 = IO<T>::ld(wc, k), pc1 = IO<T>::ld(wc, 64 + k), pc2 = IO<T>::ld(wc, 128 + k);
    float shs = IO<T>::ld(lnh_s, k), shb = IO<T>::ld(lnh_b, k);
    float scs = IO<T>::ld(lnc_s, k), scb = IO<T>::ld(lnc_b, k);
    float sos = IO<T>::ld(lno_s, k), sob = IO<T>::ld(lno_b, k);

    for (int nn = 0; nn < cnt; ++nn) {
        int i = base + nn;
        float c0 = IO<T>::ld(Cin, (size_t)i * 64 + k);
        float gi = acc0[nn] + B0 + pc0 * c0;
        float gf = acc1[nn] + B1 + pc1 * c0;
        float gc = acc2[nn] + B2;
        float vi = 1.f / (1.f + __expf(-gi));
        float vf = 1.f / (1.f + __expf(-gf));
        float c  = vf * c0 + vi * tanhf(gc);
        float go = acc3[nn] + B3 + pc2 * c;
        float vo = 1.f / (1.f + __expf(-go));
        float hh = vo * tanhf(c);
        float sh_ = hh, sh2 = hh * hh, sc_ = c, sc2 = c * c;
#pragma unroll
        for (int off = 32; off > 0; off >>= 1) {
            sh_ += __shfl_xor(sh_, off);
            sh2 += __shfl_xor(sh2, off);
            sc_ += __shfl_xor(sc_, off);
            sc2 += __shfl_xor(sc2, off);
        }
        float mh = sh_ * 0.015625f;
        float vh = sh2 * 0.015625f - mh * mh;
        float rh = rsqrtf(vh + 1e-5f);
        float mc = sc_ * 0.015625f;
        float vcv = sc2 * 0.015625f - mc * mc;
        float rc = rsqrtf(vcv + 1e-5f);
        float hn = (hh - mh) * rh;
        IO<T>::st(out_hidden, (size_t)i * 64 + k, hn * shs + shb);
        IO<T>::st(out_cell, (size_t)i * 64 + k, (c - mc) * rc * scs + scb);
        float r = hn * sos + sob;
        r = r > 0.f ? r : 0.f;
        sh_u[nn * 66 + k] = r;
        if (k < 2) sh_u[nn * 66 + 64 + k] = IO<T>::ld(skip, (size_t)i * 2 + k);
    }
    __syncthreads();
    float tacc[8] = {};
    for (int f = 0; f < 66; ++f) {
        float w = IO<T>::ld(W1, f * 64 + k);
#pragma unroll
        for (int nn = 0; nn < 8; ++nn)
            tacc[nn] = fmaf(sh_u[nn * 66 + f], w, tacc[nn]);
    }
    for (int nn = 0; nn < cnt; ++nn)
        t_out[(size_t)(base + nn) * 64 + k] = f2b(tacc[nn]);
}
__global__ __launch_bounds__(64) void dec_gates_kernel(
    const bf16* axah, const void* Cin, const void* Wx, const void* bx, const void* Wh,
    const void* bh, const void* wc, const void* bg, const void* lnh_s, const void* lnh_b,
    const void* lnc_s, const void* lnc_b, const void* lno_s, const void* lno_b,
    const void* skip, const void* W1, bf16* t_out, void* dout, int n, const int* flag) {
    if (*flag)
        gates_body<bf16>(axah, (const bf16*)Cin, (const bf16*)Wx, (const bf16*)bx,
                         (const bf16*)Wh, (const bf16*)bh, (const bf16*)wc, (const bf16*)bg,
                         (const bf16*)lnh_s, (const bf16*)lnh_b, (const bf16*)lnc_s,
                         (const bf16*)lnc_b, (const bf16*)lno_s, (const bf16*)lno_b,
                         (const bf16*)skip, (const bf16*)W1, t_out, (bf16*)dout, n);
    else
        gates_body<float>(axah, (const float*)Cin, (const float*)Wx, (const float*)bx,
                          (const float*)Wh, (const float*)bh, (const float*)wc, (const float*)bg,
                          (const float*)lnh_s, (const float*)lnh_b, (const float*)lnc_s,
                          (const float*)lnc_b, (const float*)lno_s, (const float*)lno_b,
                          (const float*)skip, (const float*)W1, t_out, (float*)dout, n);
}

template <typename T>
__device__ __forceinline__ void aggB_body(const int* __restrict__ rowstart,
                                          const int* __restrict__ csr_src,
                                          const float* __restrict__ csr_norm,
                                          const float* __restrict__ dinv,
                                          const bf16* __restrict__ t, const T* __restrict__ b1,
                                          const T* __restrict__ W2, float* __restrict__ s_out,
                                          int n) {
    int wave = threadIdx.x >> 6;
    int lane = threadIdx.x & 63;
    int i = blockIdx.x * 4 + wave;
    if (i >= n) return;
    float di = dinv[i];
    float acc = di * di * b2f(t[(size_t)i * 64 + lane]);
    int s0 = rowstart[i], s1 = rowstart[i + 1];
    for (int e = s0; e < s1; ++e)
        acc += csr_norm[e] * b2f(t[(size_t)csr_src[e] * 64 + lane]);
    float v = acc + IO<T>::ld(b1, lane);
    v = v > 0.f ? v : 0.f;
    float p = v * IO<T>::ld(W2, lane);
#pragma unroll
    for (int off = 32; off > 0; off >>= 1) p += __shfl_xor(p, off);
    if (lane == 0) s_out[i] = p;
}
__global__ __launch_bounds__(256) void dec_aggB_kernel(const int* rowstart, const int* csr_src,
                                                       const float* csr_norm, const float* dinv,
                                                       const bf16* t, const void* b1,
                                                       const void* W2, float* s_out, int n,
                                                       const int* flag) {
    if (*flag) aggB_body<bf16>(rowstart, csr_src, csr_norm, dinv, t, (const bf16*)b1, (const bf16*)W2, s_out, n);
    else       aggB_body<float>(rowstart, csr_src, csr_norm, dinv, t, (const float*)b1, (const float*)W2, s_out, n);
}

template <typename T>
__device__ __forceinline__ void aggC_body(const int* __restrict__ rowstart,
                                          const int* __restrict__ csr_src,
                                          const float* __restrict__ csr_norm,
                                          const float* __restrict__ dinv,
                                          const float* __restrict__ s_in, const T* __restrict__ X,
                                          const T* __restrict__ b2p, T* __restrict__ out0, int n) {
    int wave = threadIdx.x >> 6;
    int lane = threadIdx.x & 63;
    int i = blockIdx.x * 4 + wave;
    if (i >= n) return;
    float acc = 0.f;
    int s0 = rowstart[i], s1 = rowstart[i + 1];
    for (int e = s0 + lane; e < s1; e += 64)
        acc += csr_norm[e] * s_in[csr_src[e]];
#pragma unroll
    for (int off = 32; off > 0; off >>= 1) acc += __shfl_xor(acc, off);
    if (lane == 0) {
        float di = dinv[i];
        float r = acc + di * di * s_in[i] + IO<T>::ld(b2p, 0) + IO<T>::ld(X, (size_t)i * F_IN);
        IO<T>::st(out0, i, r);
    }
}
__global__ __launch_bounds__(256) void dec_aggC_kernel(const int* rowstart, const int* csr_src,
                                                       const float* csr_norm, const float* dinv,
                                                       const float* s_in, const void* X,
                                                       const void* b2p, void* out0, int n,
                                                       const int* flag) {
    if (*flag) aggC_body<bf16>(rowstart, csr_src, csr_norm, dinv, s_in, (const bf16*)X, (const bf16*)b2p, (bf16*)out0, n);
    else       aggC_body<float>(rowstart, csr_src, csr_norm, dinv, s_in, (const float*)X, (const float*)b2p, (float*)out0, n);
}

extern "C" void kernel_launch(void* const* d_in, const int* in_sizes, int n_in,
                              void* d_out, int out_size, void* d_ws, size_t ws_size,
                              hipStream_t stream) {
    const void* X     = d_in[0];
    const int*  ei    = (const int*)d_in[1];
    const void* ew    = d_in[2];
    const void* skip  = d_in[3];
    const void* H     = d_in[4];
    const void* C     = d_in[5];
    const void* Wx    = d_in[6];
    const void* bx    = d_in[7];
    const void* Wh    = d_in[8];
    const void* bh    = d_in[9];
    const void* wc    = d_in[10];
    const void* bg    = d_in[11];
    const void* lnh_s = d_in[12];
    const void* lnh_b = d_in[13];
    const void* lnc_s = d_in[14];
    const void* lnc_b = d_in[15];
    const void* lno_s = d_in[16];
    const void* lno_b = d_in[17];
    const void* W1    = d_in[18];
    const void* b1    = d_in[19];
    const void* W2    = d_in[20];
    const void* b2    = d_in[21];

    const int N = in_sizes[0] / F_IN;
    const int E = in_sizes[2];

    // workspace layout: ~42 MB total
    float* ws       = (float*)d_ws;
    float* dinv     = ws;                                   // N (deg_w accum -> dinv in place)
    int*   count    = (int*)(ws + (size_t)N);               // N
    int*   cursor   = (int*)(ws + (size_t)2 * N);           // N
    int*   rowstart = (int*)(ws + (size_t)3 * N);           // N+1
    int*   flag     = (int*)(ws + (size_t)4 * N + 4);       // 1
    int*   csr_src  = (int*)(ws + (size_t)4 * N + 8);       // E
    float* csr_norm = ws + (size_t)4 * N + 8 + E;           // E
    bf16*  axah     = (bf16*)(ws + (size_t)4 * N + 8 + 2 * (size_t)E);                   // 72N bf16
    bf16*  t        = (bf16*)(ws + (size_t)4 * N + 8 + 2 * (size_t)E + 36 * (size_t)N);  // 64N bf16
    float* sarr     = ws + (size_t)4 * N + 8 + 2 * (size_t)E + 68 * (size_t)N;           // N

    hipMemsetAsync(dinv, 0, (size_t)3 * N * sizeof(float), stream);

    dec_detect_kernel<<<1, 64, 0, stream>>>((const unsigned int*)X, flag);
    dec_deg_kernel<<<(E + 255) / 256, 256, 0, stream>>>(ei, ew, dinv, count, E, flag);
    dec_scan_kernel<<<1, 1024, 0, stream>>>(count, dinv, rowstart, N);
    dec_scatter_kernel<<<(E + 255) / 256, 256, 0, stream>>>(ei, ew, dinv, rowstart, cursor,
                                                            csr_src, csr_norm, E, flag);
    dec_aggA_kernel<<<(N + 3) / 4, 256, 0, stream>>>(rowstart, csr_src, csr_norm, dinv,
                                                     X, H, axah, N, flag);
    dec_gates_kernel<<<(N + 7) / 8, 64, 0, stream>>>(axah, C, Wx, bx, Wh, bh, wc, bg,
                                                     lnh_s, lnh_b, lnc_s, lnc_b, lno_s, lno_b,
                                                     skip, W1, t, d_out, N, flag);
    dec_aggB_kernel<<<(N + 3) / 4, 256, 0, stream>>>(rowstart, csr_src, csr_norm, dinv,
                                                     t, b1, W2, sarr, N, flag);
    dec_aggC_kernel<<<(N + 3) / 4, 256, 0, stream>>>(rowstart, csr_src, csr_norm, dinv,
                                                     sarr, X, b2, d_out, N, flag);
}

// Round 3
// 698.023 us; speedup vs baseline: 1.5106x; 1.5106x over previous
//
#include <hip/hip_runtime.h>
#include <hip/hip_bf16.h>

#define F_IN 8
#define HID 64

typedef __hip_bfloat16 bf16;

__device__ __forceinline__ float b2f(bf16 x) { return __bfloat162float(x); }
__device__ __forceinline__ bf16 f2b(float x) { return __float2bfloat16(x); }

template <typename T> struct IO;
template <> struct IO<bf16> {
    static __device__ __forceinline__ float ld(const bf16* p, size_t i) { return b2f(p[i]); }
    static __device__ __forceinline__ void st(bf16* p, size_t i, float v) { p[i] = f2b(v); }
};
template <> struct IO<float> {
    static __device__ __forceinline__ float ld(const float* p, size_t i) { return p[i]; }
    static __device__ __forceinline__ void st(float* p, size_t i, float v) { p[i] = v; }
};

// K0: dtype vote. bf16 data: low 16 bits of each word are a bf16 ~N(0,1) ->
// exponent in narrow band (~100%). f32 data: low bits are mantissa noise (~16%).
__global__ void dec_detect_kernel(const unsigned int* __restrict__ xraw, int* __restrict__ flag) {
    int t = threadIdx.x;
    int cnt = 0;
    for (int j = 0; j < 4; ++j) {
        unsigned w = xraw[t * 4 + j];
        unsigned lo = w & 0xFFFFu;
        unsigned e = (lo >> 7) & 0xFFu;
        if (lo == 0u || (e >= 100u && e <= 144u)) cnt++;
    }
#pragma unroll
    for (int off = 32; off > 0; off >>= 1) cnt += __shfl_xor(cnt, off);
    if (t == 0) *flag = (cnt >= 128) ? 1 : 0;
}

// K1: per-dst weighted degree + edge count
template <typename T>
__device__ __forceinline__ void deg_body(const int* __restrict__ ei, const T* __restrict__ ew,
                                         float* __restrict__ deg_w, int* __restrict__ count, int E) {
    int e = blockIdx.x * blockDim.x + threadIdx.x;
    if (e >= E) return;
    int dst = ei[E + e];
    atomicAdd(&deg_w[dst], IO<T>::ld(ew, e));
    atomicAdd(&count[dst], 1);
}
__global__ void dec_deg_kernel(const int* ei, const void* ew, float* deg_w, int* count, int E,
                               const int* flag) {
    if (*flag) deg_body<bf16>(ei, (const bf16*)ew, deg_w, count, E);
    else       deg_body<float>(ei, (const float*)ew, deg_w, count, E);
}

// K2a: per-block reduce of count -> partial[b]; dinv = rsqrt(deg_w+1) in place
__global__ __launch_bounds__(1024) void dec_scan1_kernel(const int* __restrict__ count,
                                                         float* __restrict__ dinv,
                                                         int* __restrict__ partial, int n) {
    __shared__ int sh[1024];
    int i = blockIdx.x * 1024 + threadIdx.x;
    int v = (i < n) ? count[i] : 0;
    if (i < n) dinv[i] = rsqrtf(dinv[i] + 1.0f);
    sh[threadIdx.x] = v;
    __syncthreads();
    for (int off = 512; off > 0; off >>= 1) {
        if (threadIdx.x < off) sh[threadIdx.x] += sh[threadIdx.x + off];
        __syncthreads();
    }
    if (threadIdx.x == 0) partial[blockIdx.x] = sh[0];
}

// K2b: exclusive scan of P partials (P <= 1024), single block
__global__ __launch_bounds__(1024) void dec_scan2_kernel(int* __restrict__ partial, int P) {
    __shared__ int sh[1024];
    int v = (threadIdx.x < P) ? partial[threadIdx.x] : 0;
    sh[threadIdx.x] = v;
    __syncthreads();
    int incl = v;
    for (int off = 1; off < 1024; off <<= 1) {
        int o = (threadIdx.x >= off) ? sh[threadIdx.x - off] : 0;
        __syncthreads();
        incl += o;
        sh[threadIdx.x] = incl;
        __syncthreads();
    }
    if (threadIdx.x < P) partial[threadIdx.x] = incl - v;
}

// K2c: block-local exclusive scan + partial offset -> rowstart
__global__ __launch_bounds__(1024) void dec_scan3_kernel(const int* __restrict__ count,
                                                         const int* __restrict__ partial,
                                                         int* __restrict__ rowstart, int n) {
    __shared__ int sh[1024];
    int i = blockIdx.x * 1024 + threadIdx.x;
    int v = (i < n) ? count[i] : 0;
    sh[threadIdx.x] = v;
    __syncthreads();
    int incl = v;
    for (int off = 1; off < 1024; off <<= 1) {
        int o = (threadIdx.x >= off) ? sh[threadIdx.x - off] : 0;
        __syncthreads();
        incl += o;
        sh[threadIdx.x] = incl;
        __syncthreads();
    }
    int offbase = partial[blockIdx.x];
    if (i < n) rowstart[i] = offbase + incl - v;
    if (i == n - 1) rowstart[n] = offbase + incl;
}

// K3: scatter edges into packed CSR (int2 {src, norm-as-int}); slot via atomicSub
// on count (dead after scan) -> fills each row in reverse order
template <typename T>
__device__ __forceinline__ void scatter_body(const int* __restrict__ ei, const T* __restrict__ ew,
                                             const float* __restrict__ dinv,
                                             const int* __restrict__ rowstart,
                                             int* __restrict__ count, int2* __restrict__ csr, int E) {
    int e = blockIdx.x * blockDim.x + threadIdx.x;
    if (e >= E) return;
    int src = ei[e];
    int dst = ei[E + e];
    int pos = rowstart[dst] + atomicSub(&count[dst], 1) - 1;
    int2 v;
    v.x = src;
    v.y = __float_as_int(dinv[dst] * IO<T>::ld(ew, e) * dinv[src]);
    csr[pos] = v;
}
__global__ void dec_scatter_kernel(const int* ei, const void* ew, const float* dinv,
                                   const int* rowstart, int* count, int2* csr, int E,
                                   const int* flag) {
    if (*flag) scatter_body<bf16>(ei, (const bf16*)ew, dinv, rowstart, count, csr, E);
    else       scatter_body<float>(ei, (const float*)ew, dinv, rowstart, count, csr, E);
}

// K4: fused pull agg of X (8) and H (64) -> axah[N][72] bf16. wave/node,
// lane = feature, edge loop unrolled x8 for memory-level parallelism.
template <typename T>
__device__ __forceinline__ void aggA_body(const int* __restrict__ rowstart,
                                          const int2* __restrict__ csr,
                                          const float* __restrict__ dinv,
                                          const T* __restrict__ X, const T* __restrict__ H,
                                          bf16* __restrict__ axah, int n) {
    int wave = threadIdx.x >> 6;
    int lane = threadIdx.x & 63;
    int i = blockIdx.x * 4 + wave;
    if (i >= n) return;
    float di = dinv[i];
    float self = di * di;
    float acc_h = self * IO<T>::ld(H, (size_t)i * 64 + lane);
    float acc_x = (lane < F_IN) ? self * IO<T>::ld(X, (size_t)i * F_IN + lane) : 0.f;
    int e = rowstart[i], s1 = rowstart[i + 1];
    for (; e + 8 <= s1; e += 8) {
        int2 ed[8];
#pragma unroll
        for (int j = 0; j < 8; ++j) ed[j] = csr[e + j];
        float hv[8];
#pragma unroll
        for (int j = 0; j < 8; ++j) hv[j] = IO<T>::ld(H, (size_t)ed[j].x * 64 + lane);
#pragma unroll
        for (int j = 0; j < 8; ++j) acc_h = fmaf(__int_as_float(ed[j].y), hv[j], acc_h);
        if (lane < F_IN) {
            float xv[8];
#pragma unroll
            for (int j = 0; j < 8; ++j) xv[j] = IO<T>::ld(X, (size_t)ed[j].x * F_IN + lane);
#pragma unroll
            for (int j = 0; j < 8; ++j) acc_x = fmaf(__int_as_float(ed[j].y), xv[j], acc_x);
        }
    }
    for (; e < s1; ++e) {
        int2 ed = csr[e];
        float nrm = __int_as_float(ed.y);
        acc_h = fmaf(nrm, IO<T>::ld(H, (size_t)ed.x * 64 + lane), acc_h);
        if (lane < F_IN) acc_x = fmaf(nrm, IO<T>::ld(X, (size_t)ed.x * F_IN + lane), acc_x);
    }
    axah[(size_t)i * 72 + lane] = f2b(acc_h);
    if (lane < F_IN) axah[(size_t)i * 72 + 64 + lane] = f2b(acc_x);
}
__global__ __launch_bounds__(256) void dec_aggA_kernel(const int* rowstart, const int2* csr,
                                                       const float* dinv, const void* X,
                                                       const void* H, bf16* axah, int n,
                                                       const int* flag) {
    if (*flag) aggA_body<bf16>(rowstart, csr, dinv, (const bf16*)X, (const bf16*)H, axah, n);
    else       aggA_body<float>(rowstart, csr, dinv, (const float*)X, (const float*)H, axah, n);
}

// K5: gates + peepholes + 3 LayerNorms + [relu(LNo(h)),skip]@W1 fused
template <typename T>
__device__ __forceinline__ void gates_body(
    const bf16* __restrict__ axah, const T* __restrict__ Cin,
    const T* __restrict__ Wx, const T* __restrict__ bx,
    const T* __restrict__ Wh, const T* __restrict__ bh,
    const T* __restrict__ wc, const T* __restrict__ bg,
    const T* __restrict__ lnh_s, const T* __restrict__ lnh_b,
    const T* __restrict__ lnc_s, const T* __restrict__ lnc_b,
    const T* __restrict__ lno_s, const T* __restrict__ lno_b,
    const T* __restrict__ skip, const T* __restrict__ W1,
    bf16* __restrict__ t_out, T* __restrict__ dout, int n) {
    const int k = threadIdx.x;
    const int base = blockIdx.x * 8;
    T* out_hidden = dout + n;
    T* out_cell   = dout + n + (size_t)64 * n;
    __shared__ float sh_axah[8 * 72];
    __shared__ float sh_u[8 * 66];
    int cnt = n - base; if (cnt > 8) cnt = 8; if (cnt < 0) cnt = 0;
    for (int idx = k; idx < cnt * 72; idx += 64)
        sh_axah[idx] = b2f(axah[(size_t)base * 72 + idx]);
    __syncthreads();

    float acc0[8] = {}, acc1[8] = {}, acc2[8] = {}, acc3[8] = {};
    for (int h = 0; h < HID; ++h) {
        float w0 = IO<T>::ld(Wh, 0 * 4096 + h * 64 + k);
        float w1 = IO<T>::ld(Wh, 1 * 4096 + h * 64 + k);
        float w2 = IO<T>::ld(Wh, 2 * 4096 + h * 64 + k);
        float w3 = IO<T>::ld(Wh, 3 * 4096 + h * 64 + k);
#pragma unroll
        for (int nn = 0; nn < 8; ++nn) {
            float a = sh_axah[nn * 72 + h];
            acc0[nn] = fmaf(a, w0, acc0[nn]);
            acc1[nn] = fmaf(a, w1, acc1[nn]);
            acc2[nn] = fmaf(a, w2, acc2[nn]);
            acc3[nn] = fmaf(a, w3, acc3[nn]);
        }
    }
    for (int f = 0; f < F_IN; ++f) {
        float w0 = IO<T>::ld(Wx, 0 * 512 + f * 64 + k);
        float w1 = IO<T>::ld(Wx, 1 * 512 + f * 64 + k);
        float w2 = IO<T>::ld(Wx, 2 * 512 + f * 64 + k);
        float w3 = IO<T>::ld(Wx, 3 * 512 + f * 64 + k);
#pragma unroll
        for (int nn = 0; nn < 8; ++nn) {
            float a = sh_axah[nn * 72 + 64 + f];
            acc0[nn] = fmaf(a, w0, acc0[nn]);
            acc1[nn] = fmaf(a, w1, acc1[nn]);
            acc2[nn] = fmaf(a, w2, acc2[nn]);
            acc3[nn] = fmaf(a, w3, acc3[nn]);
        }
    }

    float B0 = IO<T>::ld(bx, k)       + IO<T>::ld(bh, k)       + IO<T>::ld(bg, k);
    float B1 = IO<T>::ld(bx, 64 + k)  + IO<T>::ld(bh, 64 + k)  + IO<T>::ld(bg, 64 + k);
    float B2 = IO<T>::ld(bx, 128 + k) + IO<T>::ld(bh, 128 + k) + IO<T>::ld(bg, 128 + k);
    float B3 = IO<T>::ld(bx, 192 + k) + IO<T>::ld(bh, 192 + k) + IO<T>::ld(bg, 192 + k);
    float pc0 = IO<T>::ld(wc, k), pc1 = IO<T>::ld(wc, 64 + k), pc2 = IO<T>::ld(wc, 128 + k);
    float shs = IO<T>::ld(lnh_s, k), shb = IO<T>::ld(lnh_b, k);
    float scs = IO<T>::ld(lnc_s, k), scb = IO<T>::ld(lnc_b, k);
    float sos = IO<T>::ld(lno_s, k), sob = IO<T>::ld(lno_b, k);

    for (int nn = 0; nn < cnt; ++nn) {
        int i = base + nn;
        float c0 = IO<T>::ld(Cin, (size_t)i * 64 + k);
        float gi = acc0[nn] + B0 + pc0 * c0;
        float gf = acc1[nn] + B1 + pc1 * c0;
        float gc = acc2[nn] + B2;
        float vi = 1.f / (1.f + __expf(-gi));
        float vf = 1.f / (1.f + __expf(-gf));
        float c  = vf * c0 + vi * tanhf(gc);
        float go = acc3[nn] + B3 + pc2 * c;
        float vo = 1.f / (1.f + __expf(-go));
        float hh = vo * tanhf(c);
        float sh_ = hh, sh2 = hh * hh, sc_ = c, sc2 = c * c;
#pragma unroll
        for (int off = 32; off > 0; off >>= 1) {
            sh_ += __shfl_xor(sh_, off);
            sh2 += __shfl_xor(sh2, off);
            sc_ += __shfl_xor(sc_, off);
            sc2 += __shfl_xor(sc2, off);
        }
        float mh = sh_ * 0.015625f;
        float vh = sh2 * 0.015625f - mh * mh;
        float rh = rsqrtf(vh + 1e-5f);
        float mc = sc_ * 0.015625f;
        float vcv = sc2 * 0.015625f - mc * mc;
        float rc = rsqrtf(vcv + 1e-5f);
        float hn = (hh - mh) * rh;
        IO<T>::st(out_hidden, (size_t)i * 64 + k, hn * shs + shb);
        IO<T>::st(out_cell, (size_t)i * 64 + k, (c - mc) * rc * scs + scb);
        float r = hn * sos + sob;
        r = r > 0.f ? r : 0.f;
        sh_u[nn * 66 + k] = r;
        if (k < 2) sh_u[nn * 66 + 64 + k] = IO<T>::ld(skip, (size_t)i * 2 + k);
    }
    __syncthreads();
    float tacc[8] = {};
    for (int f = 0; f < 66; ++f) {
        float w = IO<T>::ld(W1, f * 64 + k);
#pragma unroll
        for (int nn = 0; nn < 8; ++nn)
            tacc[nn] = fmaf(sh_u[nn * 66 + f], w, tacc[nn]);
    }
    for (int nn = 0; nn < cnt; ++nn)
        t_out[(size_t)(base + nn) * 64 + k] = f2b(tacc[nn]);
}
__global__ __launch_bounds__(64) void dec_gates_kernel(
    const bf16* axah, const void* Cin, const void* Wx, const void* bx, const void* Wh,
    const void* bh, const void* wc, const void* bg, const void* lnh_s, const void* lnh_b,
    const void* lnc_s, const void* lnc_b, const void* lno_s, const void* lno_b,
    const void* skip, const void* W1, bf16* t_out, void* dout, int n, const int* flag) {
    if (*flag)
        gates_body<bf16>(axah, (const bf16*)Cin, (const bf16*)Wx, (const bf16*)bx,
                         (const bf16*)Wh, (const bf16*)bh, (const bf16*)wc, (const bf16*)bg,
                         (const bf16*)lnh_s, (const bf16*)lnh_b, (const bf16*)lnc_s,
                         (const bf16*)lnc_b, (const bf16*)lno_s, (const bf16*)lno_b,
                         (const bf16*)skip, (const bf16*)W1, t_out, (bf16*)dout, n);
    else
        gates_body<float>(axah, (const float*)Cin, (const float*)Wx, (const float*)bx,
                          (const float*)Wh, (const float*)bh, (const float*)wc, (const float*)bg,
                          (const float*)lnh_s, (const float*)lnh_b, (const float*)lnc_s,
                          (const float*)lnc_b, (const float*)lno_s, (const float*)lno_b,
                          (const float*)skip, (const float*)W1, t_out, (float*)dout, n);
}

// K6: v = relu(agg(t) + b1); s = v @ W2. Unrolled x8 like aggA.
template <typename T>
__device__ __forceinline__ void aggB_body(const int* __restrict__ rowstart,
                                          const int2* __restrict__ csr,
                                          const float* __restrict__ dinv,
                                          const bf16* __restrict__ t, const T* __restrict__ b1,
                                          const T* __restrict__ W2, float* __restrict__ s_out,
                                          int n) {
    int wave = threadIdx.x >> 6;
    int lane = threadIdx.x & 63;
    int i = blockIdx.x * 4 + wave;
    if (i >= n) return;
    float di = dinv[i];
    float acc = di * di * b2f(t[(size_t)i * 64 + lane]);
    int e = rowstart[i], s1 = rowstart[i + 1];
    for (; e + 8 <= s1; e += 8) {
        int2 ed[8];
#pragma unroll
        for (int j = 0; j < 8; ++j) ed[j] = csr[e + j];
        float tv[8];
#pragma unroll
        for (int j = 0; j < 8; ++j) tv[j] = b2f(t[(size_t)ed[j].x * 64 + lane]);
#pragma unroll
        for (int j = 0; j < 8; ++j) acc = fmaf(__int_as_float(ed[j].y), tv[j], acc);
    }
    for (; e < s1; ++e) {
        int2 ed = csr[e];
        acc = fmaf(__int_as_float(ed.y), b2f(t[(size_t)ed.x * 64 + lane]), acc);
    }
    float v = acc + IO<T>::ld(b1, lane);
    v = v > 0.f ? v : 0.f;
    float p = v * IO<T>::ld(W2, lane);
#pragma unroll
    for (int off = 32; off > 0; off >>= 1) p += __shfl_xor(p, off);
    if (lane == 0) s_out[i] = p;
}
__global__ __launch_bounds__(256) void dec_aggB_kernel(const int* rowstart, const int2* csr,
                                                       const float* dinv, const bf16* t,
                                                       const void* b1, const void* W2,
                                                       float* s_out, int n, const int* flag) {
    if (*flag) aggB_body<bf16>(rowstart, csr, dinv, t, (const bf16*)b1, (const bf16*)W2, s_out, n);
    else       aggB_body<float>(rowstart, csr, dinv, t, (const float*)b1, (const float*)W2, s_out, n);
}

// K7: out = agg(s) + b2 + X[:,0]. 16 lanes per node (avg degree ~16).
template <typename T>
__device__ __forceinline__ void aggC_body(const int* __restrict__ rowstart,
                                          const int2* __restrict__ csr,
                                          const float* __restrict__ dinv,
                                          const float* __restrict__ s_in, const T* __restrict__ X,
                                          const T* __restrict__ b2p, T* __restrict__ out0, int n) {
    int lane = threadIdx.x & 63;
    int wave = threadIdx.x >> 6;
    int sub = lane >> 4, sl = lane & 15;
    int i = (blockIdx.x * 4 + wave) * 4 + sub;
    if (i >= n) return;
    float acc = 0.f;
    int s0 = rowstart[i], s1 = rowstart[i + 1];
    for (int e = s0 + sl; e < s1; e += 16) {
        int2 ed = csr[e];
        acc = fmaf(__int_as_float(ed.y), s_in[ed.x], acc);
    }
#pragma unroll
    for (int off = 8; off > 0; off >>= 1) acc += __shfl_xor(acc, off);
    if (sl == 0) {
        float di = dinv[i];
        float r = acc + di * di * s_in[i] + IO<T>::ld(b2p, 0) + IO<T>::ld(X, (size_t)i * F_IN);
        IO<T>::st(out0, i, r);
    }
}
__global__ __launch_bounds__(256) void dec_aggC_kernel(const int* rowstart, const int2* csr,
                                                       const float* dinv, const float* s_in,
                                                       const void* X, const void* b2p,
                                                       void* out0, int n, const int* flag) {
    if (*flag) aggC_body<bf16>(rowstart, csr, dinv, s_in, (const bf16*)X, (const bf16*)b2p, (bf16*)out0, n);
    else       aggC_body<float>(rowstart, csr, dinv, s_in, (const float*)X, (const float*)b2p, (float*)out0, n);
}

extern "C" void kernel_launch(void* const* d_in, const int* in_sizes, int n_in,
                              void* d_out, int out_size, void* d_ws, size_t ws_size,
                              hipStream_t stream) {
    const void* X     = d_in[0];
    const int*  ei    = (const int*)d_in[1];
    const void* ew    = d_in[2];
    const void* skip  = d_in[3];
    const void* H     = d_in[4];
    const void* C     = d_in[5];
    const void* Wx    = d_in[6];
    const void* bx    = d_in[7];
    const void* Wh    = d_in[8];
    const void* bh    = d_in[9];
    const void* wc    = d_in[10];
    const void* bg    = d_in[11];
    const void* lnh_s = d_in[12];
    const void* lnh_b = d_in[13];
    const void* lnc_s = d_in[14];
    const void* lnc_b = d_in[15];
    const void* lno_s = d_in[16];
    const void* lno_b = d_in[17];
    const void* W1    = d_in[18];
    const void* b1    = d_in[19];
    const void* W2    = d_in[20];
    const void* b2    = d_in[21];

    const int N = in_sizes[0] / F_IN;
    const int E = in_sizes[2];
    const int P = (N + 1023) / 1024;   // scan partial blocks (<=1024 assumed)

    // workspace layout (4B units), ~42 MB total
    float* ws = (float*)d_ws;
    size_t o = 0;
    float* dinv     = ws + o;            o += (size_t)N;       // deg_w accum -> dinv in place
    int*   count    = (int*)(ws + o);    o += (size_t)N;
    int*   rowstart = (int*)(ws + o);    o += (size_t)N + 1;
    int*   partial  = (int*)(ws + o);    o += (size_t)P;
    int*   flag     = (int*)(ws + o);    o += 1;
    o = (o + 1) & ~(size_t)1;            // 8B align for int2
    int2*  csr      = (int2*)(ws + o);   o += 2 * (size_t)E;
    bf16*  axah     = (bf16*)(ws + o);   o += 36 * (size_t)N;  // 72N bf16
    bf16*  t        = (bf16*)(ws + o);   o += 32 * (size_t)N;  // 64N bf16
    float* sarr     = ws + o;            o += (size_t)N;

    // zero deg_w(dinv) + count (contiguous 2N)
    hipMemsetAsync(dinv, 0, (size_t)2 * N * sizeof(float), stream);

    dec_detect_kernel<<<1, 64, 0, stream>>>((const unsigned int*)X, flag);
    dec_deg_kernel<<<(E + 255) / 256, 256, 0, stream>>>(ei, ew, dinv, count, E, flag);
    dec_scan1_kernel<<<P, 1024, 0, stream>>>(count, dinv, partial, N);
    dec_scan2_kernel<<<1, 1024, 0, stream>>>(partial, P);
    dec_scan3_kernel<<<P, 1024, 0, stream>>>(count, partial, rowstart, N);
    dec_scatter_kernel<<<(E + 255) / 256, 256, 0, stream>>>(ei, ew, dinv, rowstart, count,
                                                            csr, E, flag);
    dec_aggA_kernel<<<(N + 3) / 4, 256, 0, stream>>>(rowstart, csr, dinv, X, H, axah, N, flag);
    dec_gates_kernel<<<(N + 7) / 8, 64, 0, stream>>>(axah, C, Wx, bx, Wh, bh, wc, bg,
                                                     lnh_s, lnh_b, lnc_s, lnc_b, lno_s, lno_b,
                                                     skip, W1, t, d_out, N, flag);
    dec_aggB_kernel<<<(N + 3) / 4, 256, 0, stream>>>(rowstart, csr, dinv, t, b1, W2, sarr,
                                                     N, flag);
    dec_aggC_kernel<<<(N + 15) / 16, 256, 0, stream>>>(rowstart, csr, dinv, sarr, X, b2,
                                                       d_out, N, flag);
}

// Round 4
// 660.674 us; speedup vs baseline: 1.5960x; 1.0565x over previous
//
#include <hip/hip_runtime.h>
#include <hip/hip_bf16.h>

#define F_IN 8
#define HID 64

typedef __hip_bfloat16 bf16;
typedef short short8 __attribute__((ext_vector_type(8)));
typedef float f32x4 __attribute__((ext_vector_type(4)));

__device__ __forceinline__ float b2f(bf16 x) { return __bfloat162float(x); }
__device__ __forceinline__ bf16 f2b(float x) { return __float2bfloat16(x); }

template <typename T> struct IO;
template <> struct IO<bf16> {
    static __device__ __forceinline__ float ld(const bf16* p, size_t i) { return b2f(p[i]); }
    static __device__ __forceinline__ void st(bf16* p, size_t i, float v) { p[i] = f2b(v); }
};
template <> struct IO<float> {
    static __device__ __forceinline__ float ld(const float* p, size_t i) { return p[i]; }
    static __device__ __forceinline__ void st(float* p, size_t i, float v) { p[i] = v; }
};

// K0: dtype vote (bf16 low-half exponent band vs f32 mantissa noise)
__global__ void dec_detect_kernel(const unsigned int* __restrict__ xraw, int* __restrict__ flag) {
    int t = threadIdx.x;
    int cnt = 0;
    for (int j = 0; j < 4; ++j) {
        unsigned w = xraw[t * 4 + j];
        unsigned lo = w & 0xFFFFu;
        unsigned e = (lo >> 7) & 0xFFu;
        if (lo == 0u || (e >= 100u && e <= 144u)) cnt++;
    }
#pragma unroll
    for (int off = 32; off > 0; off >>= 1) cnt += __shfl_xor(cnt, off);
    if (t == 0) *flag = (cnt >= 128) ? 1 : 0;
}

// K1: per-dst weighted degree + edge count
template <typename T>
__device__ __forceinline__ void deg_body(const int* __restrict__ ei, const T* __restrict__ ew,
                                         float* __restrict__ deg_w, int* __restrict__ count, int E) {
    int e = blockIdx.x * blockDim.x + threadIdx.x;
    if (e >= E) return;
    int dst = ei[E + e];
    atomicAdd(&deg_w[dst], IO<T>::ld(ew, e));
    atomicAdd(&count[dst], 1);
}
__global__ void dec_deg_kernel(const int* ei, const void* ew, float* deg_w, int* count, int E,
                               const int* flag) {
    if (*flag) deg_body<bf16>(ei, (const bf16*)ew, deg_w, count, E);
    else       deg_body<float>(ei, (const float*)ew, deg_w, count, E);
}

// K2a/b/c: multi-block exclusive scan of count -> rowstart; dinv in place
__global__ __launch_bounds__(1024) void dec_scan1_kernel(const int* __restrict__ count,
                                                         float* __restrict__ dinv,
                                                         int* __restrict__ partial, int n) {
    __shared__ int sh[1024];
    int i = blockIdx.x * 1024 + threadIdx.x;
    int v = (i < n) ? count[i] : 0;
    if (i < n) dinv[i] = rsqrtf(dinv[i] + 1.0f);
    sh[threadIdx.x] = v;
    __syncthreads();
    for (int off = 512; off > 0; off >>= 1) {
        if (threadIdx.x < off) sh[threadIdx.x] += sh[threadIdx.x + off];
        __syncthreads();
    }
    if (threadIdx.x == 0) partial[blockIdx.x] = sh[0];
}
__global__ __launch_bounds__(1024) void dec_scan2_kernel(int* __restrict__ partial, int P) {
    __shared__ int sh[1024];
    int v = (threadIdx.x < P) ? partial[threadIdx.x] : 0;
    sh[threadIdx.x] = v;
    __syncthreads();
    int incl = v;
    for (int off = 1; off < 1024; off <<= 1) {
        int o = (threadIdx.x >= off) ? sh[threadIdx.x - off] : 0;
        __syncthreads();
        incl += o;
        sh[threadIdx.x] = incl;
        __syncthreads();
    }
    if (threadIdx.x < P) partial[threadIdx.x] = incl - v;
}
__global__ __launch_bounds__(1024) void dec_scan3_kernel(const int* __restrict__ count,
                                                         const int* __restrict__ partial,
                                                         int* __restrict__ rowstart, int n) {
    __shared__ int sh[1024];
    int i = blockIdx.x * 1024 + threadIdx.x;
    int v = (i < n) ? count[i] : 0;
    sh[threadIdx.x] = v;
    __syncthreads();
    int incl = v;
    for (int off = 1; off < 1024; off <<= 1) {
        int o = (threadIdx.x >= off) ? sh[threadIdx.x - off] : 0;
        __syncthreads();
        incl += o;
        sh[threadIdx.x] = incl;
        __syncthreads();
    }
    int offbase = partial[blockIdx.x];
    if (i < n) rowstart[i] = offbase + incl - v;
    if (i == n - 1) rowstart[n] = offbase + incl;
}

// K3: scatter edges into packed CSR {src, norm}; slot via atomicSub on count
template <typename T>
__device__ __forceinline__ void scatter_body(const int* __restrict__ ei, const T* __restrict__ ew,
                                             const float* __restrict__ dinv,
                                             const int* __restrict__ rowstart,
                                             int* __restrict__ count, int2* __restrict__ csr, int E) {
    int e = blockIdx.x * blockDim.x + threadIdx.x;
    if (e >= E) return;
    int src = ei[e];
    int dst = ei[E + e];
    int pos = rowstart[dst] + atomicSub(&count[dst], 1) - 1;
    int2 v;
    v.x = src;
    v.y = __float_as_int(dinv[dst] * IO<T>::ld(ew, e) * dinv[src]);
    csr[pos] = v;
}
__global__ void dec_scatter_kernel(const int* ei, const void* ew, const float* dinv,
                                   const int* rowstart, int* count, int2* csr, int E,
                                   const int* flag) {
    if (*flag) scatter_body<bf16>(ei, (const bf16*)ew, dinv, rowstart, count, csr, E);
    else       scatter_body<float>(ei, (const float*)ew, dinv, rowstart, count, csr, E);
}

// K3b: prep packed MFMA weights + f32 param tables.
// Bp: 16 tiles x 3 ksteps x 64 lanes x 8 halves: B[k][n], k=s*32+quad*8+j, n=t*16+col
//     B[h][g*64+kk]=Wh[g][h][kk]; B[64+f][...]=Wx[g][f][kk]; rows 72..95 = 0
// W1p: 4 tiles x 3 ksteps x 64 x 8: B[k][n], k<66 -> W1[k*64+n] else 0
// Bsum[256]=bx+bh+bg; wcf[192]; lnf[384]
template <typename T>
__device__ __forceinline__ void prep_body(const T* Wx, const T* bx, const T* Wh, const T* bh,
                                          const T* wc, const T* bg,
                                          const T* lnh_s, const T* lnh_b, const T* lnc_s,
                                          const T* lnc_b, const T* lno_s, const T* lno_b,
                                          const T* W1,
                                          bf16* __restrict__ Bp, bf16* __restrict__ W1p,
                                          float* __restrict__ Bsum, float* __restrict__ wcf,
                                          float* __restrict__ lnf) {
    int idx = blockIdx.x * blockDim.x + threadIdx.x;
    if (idx < 24576) {
        int j = idx & 7, l = (idx >> 3) & 63, ts = idx >> 9;
        int t = ts / 3, s = ts % 3;
        int k = s * 32 + (l >> 4) * 8 + j;
        int ncol = t * 16 + (l & 15);
        int g = ncol >> 6, kk = ncol & 63;
        float v = 0.f;
        if (k < 64) v = IO<T>::ld(Wh, g * 4096 + k * 64 + kk);
        else if (k < 72) v = IO<T>::ld(Wx, g * 512 + (k - 64) * 64 + kk);
        Bp[idx] = f2b(v);
    } else if (idx < 30720) {
        int u = idx - 24576;
        int j = u & 7, l = (u >> 3) & 63, ts = u >> 9;
        int t = ts / 3, s = ts % 3;
        int k = s * 32 + (l >> 4) * 8 + j;
        int ncol = t * 16 + (l & 15);
        float v = (k < 66) ? IO<T>::ld(W1, k * 64 + ncol) : 0.f;
        W1p[u] = f2b(v);
    } else if (idx < 30976) {
        int p = idx - 30720;
        Bsum[p] = IO<T>::ld(bx, p) + IO<T>::ld(bh, p) + IO<T>::ld(bg, p);
    } else if (idx < 31168) {
        int p = idx - 30976;
        wcf[p] = IO<T>::ld(wc, p);
    } else if (idx < 31552) {
        int p = idx - 31168;
        int which = p >> 6, k = p & 63;
        const T* src = (which == 0) ? lnh_s : (which == 1) ? lnh_b : (which == 2) ? lnc_s
                     : (which == 3) ? lnc_b : (which == 4) ? lno_s : lno_b;
        lnf[p] = IO<T>::ld(src, k);
    }
}
__global__ void dec_prep_kernel(const void* Wx, const void* bx, const void* Wh, const void* bh,
                                const void* wc, const void* bg, const void* lnh_s,
                                const void* lnh_b, const void* lnc_s, const void* lnc_b,
                                const void* lno_s, const void* lno_b, const void* W1,
                                bf16* Bp, bf16* W1p, float* Bsum, float* wcf, float* lnf,
                                const int* flag) {
    if (*flag)
        prep_body<bf16>((const bf16*)Wx, (const bf16*)bx, (const bf16*)Wh, (const bf16*)bh,
                        (const bf16*)wc, (const bf16*)bg, (const bf16*)lnh_s, (const bf16*)lnh_b,
                        (const bf16*)lnc_s, (const bf16*)lnc_b, (const bf16*)lno_s,
                        (const bf16*)lno_b, (const bf16*)W1, Bp, W1p, Bsum, wcf, lnf);
    else
        prep_body<float>((const float*)Wx, (const float*)bx, (const float*)Wh, (const float*)bh,
                         (const float*)wc, (const float*)bg, (const float*)lnh_s, (const float*)lnh_b,
                         (const float*)lnc_s, (const float*)lnc_b, (const float*)lno_s,
                         (const float*)lno_b, (const float*)W1, Bp, W1p, Bsum, wcf, lnf);
}

// K4: fused pull agg X(8)+H(64) -> axah[N][96] bf16 (cols 72..95 zero pad)
template <typename T>
__device__ __forceinline__ void aggA_body(const int* __restrict__ rowstart,
                                          const int2* __restrict__ csr,
                                          const float* __restrict__ dinv,
                                          const T* __restrict__ X, const T* __restrict__ H,
                                          bf16* __restrict__ axah, int n) {
    int wave = threadIdx.x >> 6;
    int lane = threadIdx.x & 63;
    int i = blockIdx.x * 4 + wave;
    if (i >= n) return;
    float di = dinv[i];
    float self = di * di;
    float acc_h = self * IO<T>::ld(H, (size_t)i * 64 + lane);
    float acc_x = (lane < F_IN) ? self * IO<T>::ld(X, (size_t)i * F_IN + lane) : 0.f;
    int e = rowstart[i], s1 = rowstart[i + 1];
    for (; e + 8 <= s1; e += 8) {
        int2 ed[8];
#pragma unroll
        for (int j = 0; j < 8; ++j) ed[j] = csr[e + j];
        float hv[8];
#pragma unroll
        for (int j = 0; j < 8; ++j) hv[j] = IO<T>::ld(H, (size_t)ed[j].x * 64 + lane);
#pragma unroll
        for (int j = 0; j < 8; ++j) acc_h = fmaf(__int_as_float(ed[j].y), hv[j], acc_h);
        if (lane < F_IN) {
            float xv[8];
#pragma unroll
            for (int j = 0; j < 8; ++j) xv[j] = IO<T>::ld(X, (size_t)ed[j].x * F_IN + lane);
#pragma unroll
            for (int j = 0; j < 8; ++j) acc_x = fmaf(__int_as_float(ed[j].y), xv[j], acc_x);
        }
    }
    for (; e < s1; ++e) {
        int2 ed = csr[e];
        float nrm = __int_as_float(ed.y);
        acc_h = fmaf(nrm, IO<T>::ld(H, (size_t)ed.x * 64 + lane), acc_h);
        if (lane < F_IN) acc_x = fmaf(nrm, IO<T>::ld(X, (size_t)ed.x * F_IN + lane), acc_x);
    }
    axah[(size_t)i * 96 + lane] = f2b(acc_h);
    if (lane < F_IN) axah[(size_t)i * 96 + 64 + lane] = f2b(acc_x);
    else if (lane < 32) axah[(size_t)i * 96 + 64 + lane] = f2b(0.f);  // zero pad 72..95
}
__global__ __launch_bounds__(256) void dec_aggA_kernel(const int* rowstart, const int2* csr,
                                                       const float* dinv, const void* X,
                                                       const void* H, bf16* axah, int n,
                                                       const int* flag) {
    if (*flag) aggA_body<bf16>(rowstart, csr, dinv, (const bf16*)X, (const bf16*)H, axah, n);
    else       aggA_body<float>(rowstart, csr, dinv, (const float*)X, (const float*)H, axah, n);
}

// K5: MFMA gates GEMM [64 nodes/block] + epilogue + u@W1 GEMM.
// Wave w handles nodes base+w*16..+15. C/D layout: col=lane&15, row=quad*4+reg.
template <typename T>
__device__ __forceinline__ void gates_body(
    const bf16* __restrict__ axah, const bf16* __restrict__ Bp_g, const bf16* __restrict__ W1p_g,
    const float* __restrict__ Bsum, const float* __restrict__ wcf, const float* __restrict__ lnf,
    const T* __restrict__ Cin, const T* __restrict__ skip,
    bf16* __restrict__ t_out, T* __restrict__ dout, int n) {
    __shared__ __align__(16) short lds_bp[24576];   // 48 KB
    __shared__ __align__(16) short lds_u[64 * 96];  // 12 KB
    const int tid = threadIdx.x;
    const int w = tid >> 6, lane = tid & 63;
    const int quad = lane >> 4, col = lane & 15;
    const int base = blockIdx.x * 64;
    T* out_hidden = dout + n;
    T* out_cell   = dout + n + (size_t)64 * n;

    // stage Bp -> LDS (3072 uint4), zero u pad cols 66..95
    for (int i = tid; i < 3072; i += 256)
        ((uint4*)lds_bp)[i] = ((const uint4*)Bp_g)[i];
    for (int i = tid; i < 64 * 30; i += 256)
        lds_u[(i / 30) * 96 + 66 + (i % 30)] = 0;
    // skip -> u cols 64,65
    if (tid < 128) {
        int ln = tid >> 1, sx = tid & 1;
        int gi = base + ln;
        float v = (gi < n) ? IO<T>::ld(skip, (size_t)gi * 2 + sx) : 0.f;
        lds_u[ln * 96 + 64 + sx] = *(short*)&(*(bf16*)&(v)) ; // placeholder overwritten below
        bf16 bv = f2b(v);
        lds_u[ln * 96 + 64 + sx] = *(const short*)&bv;
    }
    __syncthreads();

    // GEMM1: A rows = nodes (m = lane&15), K=96, 16 output tiles of 16
    int arow = base + w * 16 + col;
    if (arow >= n) arow = n - 1;
    short8 afr[3];
#pragma unroll
    for (int s = 0; s < 3; ++s)
        afr[s] = *(const short8*)(axah + (size_t)arow * 96 + s * 32 + quad * 8);
    f32x4 acc[16];
#pragma unroll
    for (int t = 0; t < 16; ++t) {
        f32x4 a = {0.f, 0.f, 0.f, 0.f};
#pragma unroll
        for (int s = 0; s < 3; ++s) {
            short8 b = *(const short8*)(lds_bp + ((t * 3 + s) * 64 + lane) * 8);
            a = __builtin_amdgcn_mfma_f32_16x16x32_bf16(afr[s], b, a, 0, 0, 0);
        }
        acc[t] = a;
    }

    // epilogue: per reg (node row), per kk (k = kk*16+col)
    const int nodeb = base + w * 16 + quad * 4;
#pragma unroll
    for (int reg = 0; reg < 4; ++reg) {
        int i = nodeb + reg;
        int ic = (i < n) ? i : (n - 1);
        float cc[4], hh[4];
        float sh_ = 0.f, sh2 = 0.f, sc_ = 0.f, sc2 = 0.f;
#pragma unroll
        for (int kk = 0; kk < 4; ++kk) {
            int k = kk * 16 + col;
            float c0 = IO<T>::ld(Cin, (size_t)ic * 64 + k);
            float gi = acc[0 * 4 + kk][reg] + Bsum[k]       + wcf[k] * c0;
            float gf = acc[1 * 4 + kk][reg] + Bsum[64 + k]  + wcf[64 + k] * c0;
            float gc = acc[2 * 4 + kk][reg] + Bsum[128 + k];
            float vi = 1.f / (1.f + __expf(-gi));
            float vf = 1.f / (1.f + __expf(-gf));
            float tc = 2.f / (1.f + __expf(-2.f * gc)) - 1.f;
            float c  = vf * c0 + vi * tc;
            float go = acc[3 * 4 + kk][reg] + Bsum[192 + k] + wcf[128 + k] * c;
            float vo = 1.f / (1.f + __expf(-go));
            float th = 2.f / (1.f + __expf(-2.f * c)) - 1.f;
            float h  = vo * th;
            cc[kk] = c; hh[kk] = h;
            sh_ += h; sh2 += h * h; sc_ += c; sc2 += c * c;
        }
        // LN stats: reduce over the 16 lanes of this quad group (cols 0..15)
#pragma unroll
        for (int off = 8; off > 0; off >>= 1) {
            sh_ += __shfl_xor(sh_, off);
            sh2 += __shfl_xor(sh2, off);
            sc_ += __shfl_xor(sc_, off);
            sc2 += __shfl_xor(sc2, off);
        }
        float mh = sh_ * 0.015625f;
        float rh = rsqrtf(sh2 * 0.015625f - mh * mh + 1e-5f);
        float mc = sc_ * 0.015625f;
        float rc = rsqrtf(sc2 * 0.015625f - mc * mc + 1e-5f);
#pragma unroll
        for (int kk = 0; kk < 4; ++kk) {
            int k = kk * 16 + col;
            float hn = (hh[kk] - mh) * rh;
            if (i < n) {
                IO<T>::st(out_hidden, (size_t)i * 64 + k, hn * lnf[k] + lnf[64 + k]);
                IO<T>::st(out_cell,   (size_t)i * 64 + k,
                          (cc[kk] - mc) * rc * lnf[128 + k] + lnf[192 + k]);
            }
            float r = hn * lnf[256 + k] + lnf[320 + k];
            r = r > 0.f ? r : 0.f;
            bf16 rb = f2b(r);
            lds_u[(w * 16 + quad * 4 + reg) * 96 + k] = *(const short*)&rb;
        }
    }
    __syncthreads();

    // GEMM2: t = u @ W1  (K=96 padded from 66), 4 output tiles
    short8 a2[3];
#pragma unroll
    for (int s = 0; s < 3; ++s)
        a2[s] = *(const short8*)(lds_u + (w * 16 + col) * 96 + s * 32 + quad * 8);
#pragma unroll
    for (int t2 = 0; t2 < 4; ++t2) {
        f32x4 ta = {0.f, 0.f, 0.f, 0.f};
#pragma unroll
        for (int s = 0; s < 3; ++s) {
            short8 b = *(const short8*)(W1p_g + ((t2 * 3 + s) * 64 + lane) * 8);
            ta = __builtin_amdgcn_mfma_f32_16x16x32_bf16(a2[s], b, ta, 0, 0, 0);
        }
#pragma unroll
        for (int reg = 0; reg < 4; ++reg) {
            int i = nodeb + reg;
            if (i < n) t_out[(size_t)i * 64 + t2 * 16 + col] = f2b(ta[reg]);
        }
    }
}
__global__ __launch_bounds__(256) void dec_gates_kernel(
    const bf16* axah, const bf16* Bp, const bf16* W1p, const float* Bsum, const float* wcf,
    const float* lnf, const void* Cin, const void* skip, bf16* t_out, void* dout, int n,
    const int* flag) {
    if (*flag)
        gates_body<bf16>(axah, Bp, W1p, Bsum, wcf, lnf, (const bf16*)Cin, (const bf16*)skip,
                         t_out, (bf16*)dout, n);
    else
        gates_body<float>(axah, Bp, W1p, Bsum, wcf, lnf, (const float*)Cin, (const float*)skip,
                          t_out, (float*)dout, n);
}

// K6: v = relu(agg(t) + b1); s = v @ W2
template <typename T>
__device__ __forceinline__ void aggB_body(const int* __restrict__ rowstart,
                                          const int2* __restrict__ csr,
                                          const float* __restrict__ dinv,
                                          const bf16* __restrict__ t, const T* __restrict__ b1,
                                          const T* __restrict__ W2, float* __restrict__ s_out,
                                          int n) {
    int wave = threadIdx.x >> 6;
    int lane = threadIdx.x & 63;
    int i = blockIdx.x * 4 + wave;
    if (i >= n) return;
    float di = dinv[i];
    float acc = di * di * b2f(t[(size_t)i * 64 + lane]);
    int e = rowstart[i], s1 = rowstart[i + 1];
    for (; e + 8 <= s1; e += 8) {
        int2 ed[8];
#pragma unroll
        for (int j = 0; j < 8; ++j) ed[j] = csr[e + j];
        float tv[8];
#pragma unroll
        for (int j = 0; j < 8; ++j) tv[j] = b2f(t[(size_t)ed[j].x * 64 + lane]);
#pragma unroll
        for (int j = 0; j < 8; ++j) acc = fmaf(__int_as_float(ed[j].y), tv[j], acc);
    }
    for (; e < s1; ++e) {
        int2 ed = csr[e];
        acc = fmaf(__int_as_float(ed.y), b2f(t[(size_t)ed.x * 64 + lane]), acc);
    }
    float v = acc + IO<T>::ld(b1, lane);
    v = v > 0.f ? v : 0.f;
    float p = v * IO<T>::ld(W2, lane);
#pragma unroll
    for (int off = 32; off > 0; off >>= 1) p += __shfl_xor(p, off);
    if (lane == 0) s_out[i] = p;
}
__global__ __launch_bounds__(256) void dec_aggB_kernel(const int* rowstart, const int2* csr,
                                                       const float* dinv, const bf16* t,
                                                       const void* b1, const void* W2,
                                                       float* s_out, int n, const int* flag) {
    if (*flag) aggB_body<bf16>(rowstart, csr, dinv, t, (const bf16*)b1, (const bf16*)W2, s_out, n);
    else       aggB_body<float>(rowstart, csr, dinv, t, (const float*)b1, (const float*)W2, s_out, n);
}

// K7: out = agg(s) + b2 + X[:,0]. 16 lanes per node.
template <typename T>
__device__ __forceinline__ void aggC_body(const int* __restrict__ rowstart,
                                          const int2* __restrict__ csr,
                                          const float* __restrict__ dinv,
                                          const float* __restrict__ s_in, const T* __restrict__ X,
                                          const T* __restrict__ b2p, T* __restrict__ out0, int n) {
    int lane = threadIdx.x & 63;
    int wave = threadIdx.x >> 6;
    int sub = lane >> 4, sl = lane & 15;
    int i = (blockIdx.x * 4 + wave) * 4 + sub;
    if (i >= n) return;
    float acc = 0.f;
    int s0 = rowstart[i], s1 = rowstart[i + 1];
    for (int e = s0 + sl; e < s1; e += 16) {
        int2 ed = csr[e];
        acc = fmaf(__int_as_float(ed.y), s_in[ed.x], acc);
    }
#pragma unroll
    for (int off = 8; off > 0; off >>= 1) acc += __shfl_xor(acc, off);
    if (sl == 0) {
        float di = dinv[i];
        float r = acc + di * di * s_in[i] + IO<T>::ld(b2p, 0) + IO<T>::ld(X, (size_t)i * F_IN);
        IO<T>::st(out0, i, r);
    }
}
__global__ __launch_bounds__(256) void dec_aggC_kernel(const int* rowstart, const int2* csr,
                                                       const float* dinv, const float* s_in,
                                                       const void* X, const void* b2p,
                                                       void* out0, int n, const int* flag) {
    if (*flag) aggC_body<bf16>(rowstart, csr, dinv, s_in, (const bf16*)X, (const bf16*)b2p, (bf16*)out0, n);
    else       aggC_body<float>(rowstart, csr, dinv, s_in, (const float*)X, (const float*)b2p, (float*)out0, n);
}

extern "C" void kernel_launch(void* const* d_in, const int* in_sizes, int n_in,
                              void* d_out, int out_size, void* d_ws, size_t ws_size,
                              hipStream_t stream) {
    const void* X     = d_in[0];
    const int*  ei    = (const int*)d_in[1];
    const void* ew    = d_in[2];
    const void* skip  = d_in[3];
    const void* H     = d_in[4];
    const void* C     = d_in[5];
    const void* Wx    = d_in[6];
    const void* bx    = d_in[7];
    const void* Wh    = d_in[8];
    const void* bh    = d_in[9];
    const void* wc    = d_in[10];
    const void* bg    = d_in[11];
    const void* lnh_s = d_in[12];
    const void* lnh_b = d_in[13];
    const void* lnc_s = d_in[14];
    const void* lnc_b = d_in[15];
    const void* lno_s = d_in[16];
    const void* lno_b = d_in[17];
    const void* W1    = d_in[18];
    const void* b1    = d_in[19];
    const void* W2    = d_in[20];
    const void* b2    = d_in[21];

    const int N = in_sizes[0] / F_IN;
    const int E = in_sizes[2];
    const int P = (N + 1023) / 1024;

    // workspace layout (4B words), ~47 MB
    float* ws = (float*)d_ws;
    size_t o = 0;
    float* dinv     = ws + o;            o += (size_t)N;
    int*   count    = (int*)(ws + o);    o += (size_t)N;
    int*   rowstart = (int*)(ws + o);    o += (size_t)N + 1;
    int*   partial  = (int*)(ws + o);    o += (size_t)P;
    int*   flag     = (int*)(ws + o);    o += 1;
    o = (o + 3) & ~(size_t)3;            // 16B align
    int2*  csr      = (int2*)(ws + o);   o += 2 * (size_t)E;
    bf16*  axah     = (bf16*)(ws + o);   o += 48 * (size_t)N;   // N x 96 bf16
    bf16*  t        = (bf16*)(ws + o);   o += 32 * (size_t)N;   // N x 64 bf16
    float* sarr     = ws + o;            o += (size_t)N;
    o = (o + 3) & ~(size_t)3;
    bf16*  Bp       = (bf16*)(ws + o);   o += 12288;            // 24576 bf16
    bf16*  W1p      = (bf16*)(ws + o);   o += 3072;             // 6144 bf16
    float* Bsum     = ws + o;            o += 256;
    float* wcf      = ws + o;            o += 192;
    float* lnf      = ws + o;            o += 384;

    hipMemsetAsync(dinv, 0, (size_t)2 * N * sizeof(float), stream);

    dec_detect_kernel<<<1, 64, 0, stream>>>((const unsigned int*)X, flag);
    dec_deg_kernel<<<(E + 255) / 256, 256, 0, stream>>>(ei, ew, dinv, count, E, flag);
    dec_prep_kernel<<<124, 256, 0, stream>>>(Wx, bx, Wh, bh, wc, bg, lnh_s, lnh_b, lnc_s,
                                             lnc_b, lno_s, lno_b, W1, Bp, W1p, Bsum, wcf,
                                             lnf, flag);
    dec_scan1_kernel<<<P, 1024, 0, stream>>>(count, dinv, partial, N);
    dec_scan2_kernel<<<1, 1024, 0, stream>>>(partial, P);
    dec_scan3_kernel<<<P, 1024, 0, stream>>>(count, partial, rowstart, N);
    dec_scatter_kernel<<<(E + 255) / 256, 256, 0, stream>>>(ei, ew, dinv, rowstart, count,
                                                            csr, E, flag);
    dec_aggA_kernel<<<(N + 3) / 4, 256, 0, stream>>>(rowstart, csr, dinv, X, H, axah, N, flag);
    dec_gates_kernel<<<(N + 63) / 64, 256, 0, stream>>>(axah, Bp, W1p, Bsum, wcf, lnf, C,
                                                        skip, t, d_out, N, flag);
    dec_aggB_kernel<<<(N + 3) / 4, 256, 0, stream>>>(rowstart, csr, dinv, t, b1, W2, sarr,
                                                     N, flag);
    dec_aggC_kernel<<<(N + 15) / 16, 256, 0, stream>>>(rowstart, csr, dinv, sarr, X, b2,
                                                       d_out, N, flag);
}

// Round 5
// 584.660 us; speedup vs baseline: 1.8035x; 1.1300x over previous
//
#include <hip/hip_runtime.h>
#include <hip/hip_bf16.h>

#define F_IN 8
#define HID 64

typedef __hip_bfloat16 bf16;
typedef short short8 __attribute__((ext_vector_type(8)));
typedef float f32x4 __attribute__((ext_vector_type(4)));

__device__ __forceinline__ float b2f(bf16 x) { return __bfloat162float(x); }
__device__ __forceinline__ bf16 f2b(float x) { return __float2bfloat16(x); }

template <typename T> struct IO;
template <> struct IO<bf16> {
    static __device__ __forceinline__ float ld(const bf16* p, size_t i) { return b2f(p[i]); }
    static __device__ __forceinline__ void st(bf16* p, size_t i, float v) { p[i] = f2b(v); }
};
template <> struct IO<float> {
    static __device__ __forceinline__ float ld(const float* p, size_t i) { return p[i]; }
    static __device__ __forceinline__ void st(float* p, size_t i, float v) { p[i] = v; }
};

// K0: dtype vote (bf16 low-half exponent band vs f32 mantissa noise)
__global__ void dec_detect_kernel(const unsigned int* __restrict__ xraw, int* __restrict__ flag) {
    int t = threadIdx.x;
    int cnt = 0;
    for (int j = 0; j < 4; ++j) {
        unsigned w = xraw[t * 4 + j];
        unsigned lo = w & 0xFFFFu;
        unsigned e = (lo >> 7) & 0xFFu;
        if (lo == 0u || (e >= 100u && e <= 144u)) cnt++;
    }
#pragma unroll
    for (int off = 32; off > 0; off >>= 1) cnt += __shfl_xor(cnt, off);
    if (t == 0) *flag = (cnt >= 128) ? 1 : 0;
}

// K1: ONE packed u64 atomic per edge: count in bits [42,63], weighted degree as
// 42-bit fixed point (2^-20) in bits [0,41]. Halves atomic traffic vs 2 arrays.
template <typename T>
__device__ __forceinline__ void deg_body(const int* __restrict__ ei, const T* __restrict__ ew,
                                         unsigned long long* __restrict__ packed, int E) {
    int e = blockIdx.x * blockDim.x + threadIdx.x;
    if (e >= E) return;
    int dst = ei[E + e];
    float w = IO<T>::ld(ew, e);
    unsigned wfix = (unsigned)(w * 1048576.f + 0.5f);
    atomicAdd(&packed[dst], (1ULL << 42) | (unsigned long long)wfix);
}
__global__ void dec_deg_kernel(const int* ei, const void* ew, unsigned long long* packed,
                               int E, const int* flag) {
    if (*flag) deg_body<bf16>(ei, (const bf16*)ew, packed, E);
    else       deg_body<float>(ei, (const float*)ew, packed, E);
}

// K2a: unpack count/deg -> count[], dinv[]; per-block reduce -> partial[b]
__global__ __launch_bounds__(1024) void dec_scan1_kernel(const unsigned long long* __restrict__ packed,
                                                         int* __restrict__ count,
                                                         float* __restrict__ dinv,
                                                         int* __restrict__ partial, int n) {
    __shared__ int sh[1024];
    int i = blockIdx.x * 1024 + threadIdx.x;
    int v = 0;
    if (i < n) {
        unsigned long long pk = packed[i];
        v = (int)(pk >> 42);
        float deg = (float)(pk & 0x3FFFFFFFFFFULL) * (1.0f / 1048576.0f);
        dinv[i] = rsqrtf(deg + 1.0f);   // +1 self loop
        count[i] = v;
    }
    sh[threadIdx.x] = v;
    __syncthreads();
    for (int off = 512; off > 0; off >>= 1) {
        if (threadIdx.x < off) sh[threadIdx.x] += sh[threadIdx.x + off];
        __syncthreads();
    }
    if (threadIdx.x == 0) partial[blockIdx.x] = sh[0];
}
__global__ __launch_bounds__(1024) void dec_scan2_kernel(int* __restrict__ partial, int P) {
    __shared__ int sh[1024];
    int v = (threadIdx.x < P) ? partial[threadIdx.x] : 0;
    sh[threadIdx.x] = v;
    __syncthreads();
    int incl = v;
    for (int off = 1; off < 1024; off <<= 1) {
        int o = (threadIdx.x >= off) ? sh[threadIdx.x - off] : 0;
        __syncthreads();
        incl += o;
        sh[threadIdx.x] = incl;
        __syncthreads();
    }
    if (threadIdx.x < P) partial[threadIdx.x] = incl - v;
}
__global__ __launch_bounds__(1024) void dec_scan3_kernel(const int* __restrict__ count,
                                                         const int* __restrict__ partial,
                                                         int* __restrict__ rowstart, int n) {
    __shared__ int sh[1024];
    int i = blockIdx.x * 1024 + threadIdx.x;
    int v = (i < n) ? count[i] : 0;
    sh[threadIdx.x] = v;
    __syncthreads();
    int incl = v;
    for (int off = 1; off < 1024; off <<= 1) {
        int o = (threadIdx.x >= off) ? sh[threadIdx.x - off] : 0;
        __syncthreads();
        incl += o;
        sh[threadIdx.x] = incl;
        __syncthreads();
    }
    int offbase = partial[blockIdx.x];
    if (i < n) rowstart[i] = offbase + incl - v;
    if (i == n - 1) rowstart[n] = offbase + incl;
}

// K3: scatter edges into packed CSR {src, norm}; slot via atomicSub on count
template <typename T>
__device__ __forceinline__ void scatter_body(const int* __restrict__ ei, const T* __restrict__ ew,
                                             const float* __restrict__ dinv,
                                             const int* __restrict__ rowstart,
                                             int* __restrict__ count, int2* __restrict__ csr, int E) {
    int e = blockIdx.x * blockDim.x + threadIdx.x;
    if (e >= E) return;
    int src = ei[e];
    int dst = ei[E + e];
    int pos = rowstart[dst] + atomicSub(&count[dst], 1) - 1;
    int2 v;
    v.x = src;
    v.y = __float_as_int(dinv[dst] * IO<T>::ld(ew, e) * dinv[src]);
    csr[pos] = v;
}
__global__ void dec_scatter_kernel(const int* ei, const void* ew, const float* dinv,
                                   const int* rowstart, int* count, int2* csr, int E,
                                   const int* flag) {
    if (*flag) scatter_body<bf16>(ei, (const bf16*)ew, dinv, rowstart, count, csr, E);
    else       scatter_body<float>(ei, (const float*)ew, dinv, rowstart, count, csr, E);
}

// K3b: prep packed MFMA weights + f32 param tables.
template <typename T>
__device__ __forceinline__ void prep_body(const T* Wx, const T* bx, const T* Wh, const T* bh,
                                          const T* wc, const T* bg,
                                          const T* lnh_s, const T* lnh_b, const T* lnc_s,
                                          const T* lnc_b, const T* lno_s, const T* lno_b,
                                          const T* W1,
                                          bf16* __restrict__ Bp, bf16* __restrict__ W1p,
                                          float* __restrict__ Bsum, float* __restrict__ wcf,
                                          float* __restrict__ lnf) {
    int idx = blockIdx.x * blockDim.x + threadIdx.x;
    if (idx < 24576) {
        int j = idx & 7, l = (idx >> 3) & 63, ts = idx >> 9;
        int t = ts / 3, s = ts % 3;
        int k = s * 32 + (l >> 4) * 8 + j;
        int ncol = t * 16 + (l & 15);
        int g = ncol >> 6, kk = ncol & 63;
        float v = 0.f;
        if (k < 64) v = IO<T>::ld(Wh, g * 4096 + k * 64 + kk);
        else if (k < 72) v = IO<T>::ld(Wx, g * 512 + (k - 64) * 64 + kk);
        Bp[idx] = f2b(v);
    } else if (idx < 30720) {
        int u = idx - 24576;
        int j = u & 7, l = (u >> 3) & 63, ts = u >> 9;
        int t = ts / 3, s = ts % 3;
        int k = s * 32 + (l >> 4) * 8 + j;
        int ncol = t * 16 + (l & 15);
        float v = (k < 66) ? IO<T>::ld(W1, k * 64 + ncol) : 0.f;
        W1p[u] = f2b(v);
    } else if (idx < 30976) {
        int p = idx - 30720;
        Bsum[p] = IO<T>::ld(bx, p) + IO<T>::ld(bh, p) + IO<T>::ld(bg, p);
    } else if (idx < 31168) {
        int p = idx - 30976;
        wcf[p] = IO<T>::ld(wc, p);
    } else if (idx < 31552) {
        int p = idx - 31168;
        int which = p >> 6, k = p & 63;
        const T* src = (which == 0) ? lnh_s : (which == 1) ? lnh_b : (which == 2) ? lnc_s
                     : (which == 3) ? lnc_b : (which == 4) ? lno_s : lno_b;
        lnf[p] = IO<T>::ld(src, k);
    }
}
__global__ void dec_prep_kernel(const void* Wx, const void* bx, const void* Wh, const void* bh,
                                const void* wc, const void* bg, const void* lnh_s,
                                const void* lnh_b, const void* lnc_s, const void* lnc_b,
                                const void* lno_s, const void* lno_b, const void* W1,
                                bf16* Bp, bf16* W1p, float* Bsum, float* wcf, float* lnf,
                                const int* flag) {
    if (*flag)
        prep_body<bf16>((const bf16*)Wx, (const bf16*)bx, (const bf16*)Wh, (const bf16*)bh,
                        (const bf16*)wc, (const bf16*)bg, (const bf16*)lnh_s, (const bf16*)lnh_b,
                        (const bf16*)lnc_s, (const bf16*)lnc_b, (const bf16*)lno_s,
                        (const bf16*)lno_b, (const bf16*)W1, Bp, W1p, Bsum, wcf, lnf);
    else
        prep_body<float>((const float*)Wx, (const float*)bx, (const float*)Wh, (const float*)bh,
                         (const float*)wc, (const float*)bg, (const float*)lnh_s, (const float*)lnh_b,
                         (const float*)lnc_s, (const float*)lnc_b, (const float*)lno_s,
                         (const float*)lno_b, (const float*)W1, Bp, W1p, Bsum, wcf, lnf);
}

// K4: fused pull agg X(8)+H(64) -> axah[N][96] bf16 (cols 72..95 zero pad)
template <typename T>
__device__ __forceinline__ void aggA_body(const int* __restrict__ rowstart,
                                          const int2* __restrict__ csr,
                                          const float* __restrict__ dinv,
                                          const T* __restrict__ X, const T* __restrict__ H,
                                          bf16* __restrict__ axah, int n) {
    int wave = threadIdx.x >> 6;
    int lane = threadIdx.x & 63;
    int i = blockIdx.x * 4 + wave;
    if (i >= n) return;
    float di = dinv[i];
    float self = di * di;
    float acc_h = self * IO<T>::ld(H, (size_t)i * 64 + lane);
    float acc_x = (lane < F_IN) ? self * IO<T>::ld(X, (size_t)i * F_IN + lane) : 0.f;
    int e = rowstart[i], s1 = rowstart[i + 1];
    for (; e + 8 <= s1; e += 8) {
        int2 ed[8];
#pragma unroll
        for (int j = 0; j < 8; ++j) ed[j] = csr[e + j];
        float hv[8];
#pragma unroll
        for (int j = 0; j < 8; ++j) hv[j] = IO<T>::ld(H, (size_t)ed[j].x * 64 + lane);
#pragma unroll
        for (int j = 0; j < 8; ++j) acc_h = fmaf(__int_as_float(ed[j].y), hv[j], acc_h);
        if (lane < F_IN) {
            float xv[8];
#pragma unroll
            for (int j = 0; j < 8; ++j) xv[j] = IO<T>::ld(X, (size_t)ed[j].x * F_IN + lane);
#pragma unroll
            for (int j = 0; j < 8; ++j) acc_x = fmaf(__int_as_float(ed[j].y), xv[j], acc_x);
        }
    }
    for (; e < s1; ++e) {
        int2 ed = csr[e];
        float nrm = __int_as_float(ed.y);
        acc_h = fmaf(nrm, IO<T>::ld(H, (size_t)ed.x * 64 + lane), acc_h);
        if (lane < F_IN) acc_x = fmaf(nrm, IO<T>::ld(X, (size_t)ed.x * F_IN + lane), acc_x);
    }
    axah[(size_t)i * 96 + lane] = f2b(acc_h);
    if (lane < F_IN) axah[(size_t)i * 96 + 64 + lane] = f2b(acc_x);
    else if (lane < 32) axah[(size_t)i * 96 + 64 + lane] = f2b(0.f);  // zero pad 72..95
}
__global__ __launch_bounds__(256) void dec_aggA_kernel(const int* rowstart, const int2* csr,
                                                       const float* dinv, const void* X,
                                                       const void* H, bf16* axah, int n,
                                                       const int* flag) {
    if (*flag) aggA_body<bf16>(rowstart, csr, dinv, (const bf16*)X, (const bf16*)H, axah, n);
    else       aggA_body<float>(rowstart, csr, dinv, (const float*)X, (const float*)H, axah, n);
}

// K5: MFMA gates GEMM [64 nodes/block] + epilogue + u@W1 GEMM.
// C/D layout: col=lane&15, row=quad*4+reg.
template <typename T>
__device__ __forceinline__ void gates_body(
    const bf16* __restrict__ axah, const bf16* __restrict__ Bp_g, const bf16* __restrict__ W1p_g,
    const float* __restrict__ Bsum, const float* __restrict__ wcf, const float* __restrict__ lnf,
    const T* __restrict__ Cin, const T* __restrict__ skip,
    bf16* __restrict__ t_out, T* __restrict__ dout, int n) {
    __shared__ __align__(16) short lds_bp[24576];   // 48 KB
    __shared__ __align__(16) short lds_u[64 * 96];  // 12 KB
    const int tid = threadIdx.x;
    const int w = tid >> 6, lane = tid & 63;
    const int quad = lane >> 4, col = lane & 15;
    const int base = blockIdx.x * 64;
    T* out_hidden = dout + n;
    T* out_cell   = dout + n + (size_t)64 * n;

    for (int i = tid; i < 3072; i += 256)
        ((uint4*)lds_bp)[i] = ((const uint4*)Bp_g)[i];
    for (int i = tid; i < 64 * 30; i += 256)
        lds_u[(i / 30) * 96 + 66 + (i % 30)] = 0;
    if (tid < 128) {
        int ln = tid >> 1, sx = tid & 1;
        int gi = base + ln;
        float v = (gi < n) ? IO<T>::ld(skip, (size_t)gi * 2 + sx) : 0.f;
        bf16 bv = f2b(v);
        lds_u[ln * 96 + 64 + sx] = *(const short*)&bv;
    }
    __syncthreads();

    int arow = base + w * 16 + col;
    if (arow >= n) arow = n - 1;
    short8 afr[3];
#pragma unroll
    for (int s = 0; s < 3; ++s)
        afr[s] = *(const short8*)(axah + (size_t)arow * 96 + s * 32 + quad * 8);
    f32x4 acc[16];
#pragma unroll
    for (int t = 0; t < 16; ++t) {
        f32x4 a = {0.f, 0.f, 0.f, 0.f};
#pragma unroll
        for (int s = 0; s < 3; ++s) {
            short8 b = *(const short8*)(lds_bp + ((t * 3 + s) * 64 + lane) * 8);
            a = __builtin_amdgcn_mfma_f32_16x16x32_bf16(afr[s], b, a, 0, 0, 0);
        }
        acc[t] = a;
    }

    const int nodeb = base + w * 16 + quad * 4;
#pragma unroll
    for (int reg = 0; reg < 4; ++reg) {
        int i = nodeb + reg;
        int ic = (i < n) ? i : (n - 1);
        float cc[4], hh[4];
        float sh_ = 0.f, sh2 = 0.f, sc_ = 0.f, sc2 = 0.f;
#pragma unroll
        for (int kk = 0; kk < 4; ++kk) {
            int k = kk * 16 + col;
            float c0 = IO<T>::ld(Cin, (size_t)ic * 64 + k);
            float gi = acc[0 * 4 + kk][reg] + Bsum[k]       + wcf[k] * c0;
            float gf = acc[1 * 4 + kk][reg] + Bsum[64 + k]  + wcf[64 + k] * c0;
            float gc = acc[2 * 4 + kk][reg] + Bsum[128 + k];
            float vi = 1.f / (1.f + __expf(-gi));
            float vf = 1.f / (1.f + __expf(-gf));
            float tc = 2.f / (1.f + __expf(-2.f * gc)) - 1.f;
            float c  = vf * c0 + vi * tc;
            float go = acc[3 * 4 + kk][reg] + Bsum[192 + k] + wcf[128 + k] * c;
            float vo = 1.f / (1.f + __expf(-go));
            float th = 2.f / (1.f + __expf(-2.f * c)) - 1.f;
            float h  = vo * th;
            cc[kk] = c; hh[kk] = h;
            sh_ += h; sh2 += h * h; sc_ += c; sc2 += c * c;
        }
#pragma unroll
        for (int off = 8; off > 0; off >>= 1) {
            sh_ += __shfl_xor(sh_, off);
            sh2 += __shfl_xor(sh2, off);
            sc_ += __shfl_xor(sc_, off);
            sc2 += __shfl_xor(sc2, off);
        }
        float mh = sh_ * 0.015625f;
        float rh = rsqrtf(sh2 * 0.015625f - mh * mh + 1e-5f);
        float mc = sc_ * 0.015625f;
        float rc = rsqrtf(sc2 * 0.015625f - mc * mc + 1e-5f);
#pragma unroll
        for (int kk = 0; kk < 4; ++kk) {
            int k = kk * 16 + col;
            float hn = (hh[kk] - mh) * rh;
            if (i < n) {
                IO<T>::st(out_hidden, (size_t)i * 64 + k, hn * lnf[k] + lnf[64 + k]);
                IO<T>::st(out_cell,   (size_t)i * 64 + k,
                          (cc[kk] - mc) * rc * lnf[128 + k] + lnf[192 + k]);
            }
            float r = hn * lnf[256 + k] + lnf[320 + k];
            r = r > 0.f ? r : 0.f;
            bf16 rb = f2b(r);
            lds_u[(w * 16 + quad * 4 + reg) * 96 + k] = *(const short*)&rb;
        }
    }
    __syncthreads();

    short8 a2[3];
#pragma unroll
    for (int s = 0; s < 3; ++s)
        a2[s] = *(const short8*)(lds_u + (w * 16 + col) * 96 + s * 32 + quad * 8);
#pragma unroll
    for (int t2 = 0; t2 < 4; ++t2) {
        f32x4 ta = {0.f, 0.f, 0.f, 0.f};
#pragma unroll
        for (int s = 0; s < 3; ++s) {
            short8 b = *(const short8*)(W1p_g + ((t2 * 3 + s) * 64 + lane) * 8);
            ta = __builtin_amdgcn_mfma_f32_16x16x32_bf16(a2[s], b, ta, 0, 0, 0);
        }
#pragma unroll
        for (int reg = 0; reg < 4; ++reg) {
            int i = nodeb + reg;
            if (i < n) t_out[(size_t)i * 64 + t2 * 16 + col] = f2b(ta[reg]);
        }
    }
}
__global__ __launch_bounds__(256) void dec_gates_kernel(
    const bf16* axah, const bf16* Bp, const bf16* W1p, const float* Bsum, const float* wcf,
    const float* lnf, const void* Cin, const void* skip, bf16* t_out, void* dout, int n,
    const int* flag) {
    if (*flag)
        gates_body<bf16>(axah, Bp, W1p, Bsum, wcf, lnf, (const bf16*)Cin, (const bf16*)skip,
                         t_out, (bf16*)dout, n);
    else
        gates_body<float>(axah, Bp, W1p, Bsum, wcf, lnf, (const float*)Cin, (const float*)skip,
                          t_out, (float*)dout, n);
}

// K6: v = relu(agg(t) + b1); s = v @ W2
template <typename T>
__device__ __forceinline__ void aggB_body(const int* __restrict__ rowstart,
                                          const int2* __restrict__ csr,
                                          const float* __restrict__ dinv,
                                          const bf16* __restrict__ t, const T* __restrict__ b1,
                                          const T* __restrict__ W2, float* __restrict__ s_out,
                                          int n) {
    int wave = threadIdx.x >> 6;
    int lane = threadIdx.x & 63;
    int i = blockIdx.x * 4 + wave;
    if (i >= n) return;
    float di = dinv[i];
    float acc = di * di * b2f(t[(size_t)i * 64 + lane]);
    int e = rowstart[i], s1 = rowstart[i + 1];
    for (; e + 8 <= s1; e += 8) {
        int2 ed[8];
#pragma unroll
        for (int j = 0; j < 8; ++j) ed[j] = csr[e + j];
        float tv[8];
#pragma unroll
        for (int j = 0; j < 8; ++j) tv[j] = b2f(t[(size_t)ed[j].x * 64 + lane]);
#pragma unroll
        for (int j = 0; j < 8; ++j) acc = fmaf(__int_as_float(ed[j].y), tv[j], acc);
    }
    for (; e < s1; ++e) {
        int2 ed = csr[e];
        acc = fmaf(__int_as_float(ed.y), b2f(t[(size_t)ed.x * 64 + lane]), acc);
    }
    float v = acc + IO<T>::ld(b1, lane);
    v = v > 0.f ? v : 0.f;
    float p = v * IO<T>::ld(W2, lane);
#pragma unroll
    for (int off = 32; off > 0; off >>= 1) p += __shfl_xor(p, off);
    if (lane == 0) s_out[i] = p;
}
__global__ __launch_bounds__(256) void dec_aggB_kernel(const int* rowstart, const int2* csr,
                                                       const float* dinv, const bf16* t,
                                                       const void* b1, const void* W2,
                                                       float* s_out, int n, const int* flag) {
    if (*flag) aggB_body<bf16>(rowstart, csr, dinv, t, (const bf16*)b1, (const bf16*)W2, s_out, n);
    else       aggB_body<float>(rowstart, csr, dinv, t, (const float*)b1, (const float*)W2, s_out, n);
}

// K7: out = agg(s) + b2 + X[:,0]. 16 lanes per node.
template <typename T>
__device__ __forceinline__ void aggC_body(const int* __restrict__ rowstart,
                                          const int2* __restrict__ csr,
                                          const float* __restrict__ dinv,
                                          const float* __restrict__ s_in, const T* __restrict__ X,
                                          const T* __restrict__ b2p, T* __restrict__ out0, int n) {
    int lane = threadIdx.x & 63;
    int wave = threadIdx.x >> 6;
    int sub = lane >> 4, sl = lane & 15;
    int i = (blockIdx.x * 4 + wave) * 4 + sub;
    if (i >= n) return;
    float acc = 0.f;
    int s0 = rowstart[i], s1 = rowstart[i + 1];
    for (int e = s0 + sl; e < s1; e += 16) {
        int2 ed = csr[e];
        acc = fmaf(__int_as_float(ed.y), s_in[ed.x], acc);
    }
#pragma unroll
    for (int off = 8; off > 0; off >>= 1) acc += __shfl_xor(acc, off);
    if (sl == 0) {
        float di = dinv[i];
        float r = acc + di * di * s_in[i] + IO<T>::ld(b2p, 0) + IO<T>::ld(X, (size_t)i * F_IN);
        IO<T>::st(out0, i, r);
    }
}
__global__ __launch_bounds__(256) void dec_aggC_kernel(const int* rowstart, const int2* csr,
                                                       const float* dinv, const float* s_in,
                                                       const void* X, const void* b2p,
                                                       void* out0, int n, const int* flag) {
    if (*flag) aggC_body<bf16>(rowstart, csr, dinv, s_in, (const bf16*)X, (const bf16*)b2p, (bf16*)out0, n);
    else       aggC_body<float>(rowstart, csr, dinv, s_in, (const float*)X, (const float*)b2p, (float*)out0, n);
}

extern "C" void kernel_launch(void* const* d_in, const int* in_sizes, int n_in,
                              void* d_out, int out_size, void* d_ws, size_t ws_size,
                              hipStream_t stream) {
    const void* X     = d_in[0];
    const int*  ei    = (const int*)d_in[1];
    const void* ew    = d_in[2];
    const void* skip  = d_in[3];
    const void* H     = d_in[4];
    const void* C     = d_in[5];
    const void* Wx    = d_in[6];
    const void* bx    = d_in[7];
    const void* Wh    = d_in[8];
    const void* bh    = d_in[9];
    const void* wc    = d_in[10];
    const void* bg    = d_in[11];
    const void* lnh_s = d_in[12];
    const void* lnh_b = d_in[13];
    const void* lnc_s = d_in[14];
    const void* lnc_b = d_in[15];
    const void* lno_s = d_in[16];
    const void* lno_b = d_in[17];
    const void* W1    = d_in[18];
    const void* b1    = d_in[19];
    const void* W2    = d_in[20];
    const void* b2    = d_in[21];

    const int N = in_sizes[0] / F_IN;
    const int E = in_sizes[2];
    const int P = (N + 1023) / 1024;

    // workspace layout (4B words)
    float* ws = (float*)d_ws;
    size_t o = 0;
    unsigned long long* packed = (unsigned long long*)(ws + o); o += 2 * (size_t)N;  // u64[N]
    float* dinv     = ws + o;            o += (size_t)N;
    int*   count    = (int*)(ws + o);    o += (size_t)N;
    int*   rowstart = (int*)(ws + o);    o += (size_t)N + 1;
    int*   partial  = (int*)(ws + o);    o += (size_t)P;
    int*   flag     = (int*)(ws + o);    o += 1;
    o = (o + 3) & ~(size_t)3;            // 16B align
    int2*  csr      = (int2*)(ws + o);   o += 2 * (size_t)E;
    bf16*  axah     = (bf16*)(ws + o);   o += 48 * (size_t)N;   // N x 96 bf16
    bf16*  t        = (bf16*)(ws + o);   o += 32 * (size_t)N;   // N x 64 bf16
    float* sarr     = ws + o;            o += (size_t)N;
    o = (o + 3) & ~(size_t)3;
    bf16*  Bp       = (bf16*)(ws + o);   o += 12288;
    bf16*  W1p      = (bf16*)(ws + o);   o += 3072;
    float* Bsum     = ws + o;            o += 256;
    float* wcf      = ws + o;            o += 192;
    float* lnf      = ws + o;            o += 384;

    hipMemsetAsync(packed, 0, (size_t)N * sizeof(unsigned long long), stream);

    dec_detect_kernel<<<1, 64, 0, stream>>>((const unsigned int*)X, flag);
    dec_deg_kernel<<<(E + 255) / 256, 256, 0, stream>>>(ei, ew, packed, E, flag);
    dec_prep_kernel<<<124, 256, 0, stream>>>(Wx, bx, Wh, bh, wc, bg, lnh_s, lnh_b, lnc_s,
                                             lnc_b, lno_s, lno_b, W1, Bp, W1p, Bsum, wcf,
                                             lnf, flag);
    dec_scan1_kernel<<<P, 1024, 0, stream>>>(packed, count, dinv, partial, N);
    dec_scan2_kernel<<<1, 1024, 0, stream>>>(partial, P);
    dec_scan3_kernel<<<P, 1024, 0, stream>>>(count, partial, rowstart, N);
    dec_scatter_kernel<<<(E + 255) / 256, 256, 0, stream>>>(ei, ew, dinv, rowstart, count,
                                                            csr, E, flag);
    dec_aggA_kernel<<<(N + 3) / 4, 256, 0, stream>>>(rowstart, csr, dinv, X, H, axah, N, flag);
    dec_gates_kernel<<<(N + 63) / 64, 256, 0, stream>>>(axah, Bp, W1p, Bsum, wcf, lnf, C,
                                                        skip, t, d_out, N, flag);
    dec_aggB_kernel<<<(N + 3) / 4, 256, 0, stream>>>(rowstart, csr, dinv, t, b1, W2, sarr,
                                                     N, flag);
    dec_aggC_kernel<<<(N + 15) / 16, 256, 0, stream>>>(rowstart, csr, dinv, sarr, X, b2,
                                                       d_out, N, flag);
}